// Round 1
// baseline (1135.582 us; speedup 1.0000x reference)
//
#include <hip/hip_runtime.h>
#include <hip/hip_bf16.h>
#include <stdint.h>
#include <stddef.h>

#define GLOBAL_AS __attribute__((address_space(1)))
#define LDS_AS __attribute__((address_space(3)))

typedef __attribute__((ext_vector_type(4))) float f32x4;
typedef __attribute__((ext_vector_type(8))) short bf16x8;

__device__ __forceinline__ unsigned short f2bf(float f) {
  unsigned u = __float_as_uint(f);
  u += 0x7FFFu + ((u >> 16) & 1u);   // round-to-nearest-even
  return (unsigned short)(u >> 16);
}

__device__ __forceinline__ void load_lds16(const void* g, void* l) {
  __builtin_amdgcn_global_load_lds((const GLOBAL_AS void*)g, (LDS_AS void*)l, 16, 0, 0);
}

// ---------------------------------------------------------------------------
// Detect whether the ternary weight arrays were pushed as int8 or int32.
// If int32, every word is in {-1,0,1}. If int8, a word is 4 packed ternary
// bytes -> valid int32 ternary with prob ~0.037 per word; 4096 words all
// valid has prob ~0. flag: 1 = int32, 0 = int8.
// ---------------------------------------------------------------------------
__global__ __launch_bounds__(256) void detect_dtype_k(const int* __restrict__ w,
                                                      int* __restrict__ flag) {
  __shared__ int bad;
  if (threadIdx.x == 0) bad = 0;
  __syncthreads();
  int b = 0;
  for (int i = threadIdx.x; i < 4096; i += 256) {
    int v = w[i];
    if (v < -1 || v > 1) b = 1;
  }
  if (b) bad = 1;  // benign same-value race
  __syncthreads();
  if (threadIdx.x == 0) *flag = bad ? 0 : 1;
}

// ---------------------------------------------------------------------------
// x0[t][h] = bf16(emb[ids[t]][h]);  one block per token, 8 floats/thread
// ---------------------------------------------------------------------------
__global__ __launch_bounds__(256) void gather_emb_k(const int* __restrict__ ids,
                                                    const float* __restrict__ emb,
                                                    unsigned short* __restrict__ x) {
  const int t = blockIdx.x;
  const int row = ids[t];
  const float4* src = (const float4*)(emb + (size_t)row * 2048);
  const int e = threadIdx.x;
  float4 a = src[e * 2], b = src[e * 2 + 1];
  uint4 o;
  o.x = f2bf(a.x) | ((unsigned)f2bf(a.y) << 16);
  o.y = f2bf(a.z) | ((unsigned)f2bf(a.w) << 16);
  o.z = f2bf(b.x) | ((unsigned)f2bf(b.y) << 16);
  o.w = f2bf(b.z) | ((unsigned)f2bf(b.w) << 16);
  *(uint4*)(x + (size_t)t * 2048 + e * 8) = o;
}

// ---------------------------------------------------------------------------
// ternary int8-or-int32 -> bf16 (-1,0,+1 exact).  8 elems/thread.
// n must be divisible by 2048 (grid = n/2048 blocks of 256).
// ---------------------------------------------------------------------------
__global__ __launch_bounds__(256) void convert_w_k(const void* __restrict__ src,
                                                   unsigned short* __restrict__ dst,
                                                   const int* __restrict__ flag) {
  const long long idx = ((long long)blockIdx.x * 256 + threadIdx.x) * 8;
  int v[8];
  if (*flag) {  // int32 storage
    const int* s = (const int*)src + idx;
    const int4 a = *(const int4*)s;
    const int4 b = *(const int4*)(s + 4);
    v[0] = a.x; v[1] = a.y; v[2] = a.z; v[3] = a.w;
    v[4] = b.x; v[5] = b.y; v[6] = b.z; v[7] = b.w;
  } else {      // int8 storage
    const uint2 u = *(const uint2*)((const char*)src + idx);
    v[0] = (char)(u.x); v[1] = (char)(u.x >> 8); v[2] = (char)(u.x >> 16); v[3] = (char)(u.x >> 24);
    v[4] = (char)(u.y); v[5] = (char)(u.y >> 8); v[6] = (char)(u.y >> 16); v[7] = (char)(u.y >> 24);
  }
  unsigned short o[8];
  #pragma unroll
  for (int k = 0; k < 8; ++k)
    o[k] = (v[k] == 0) ? 0 : ((v[k] > 0) ? 0x3F80 : 0xBF80);
  uint4 w;
  w.x = o[0] | ((unsigned)o[1] << 16);
  w.y = o[2] | ((unsigned)o[3] << 16);
  w.z = o[4] | ((unsigned)o[5] << 16);
  w.w = o[6] | ((unsigned)o[7] << 16);
  *(uint4*)(dst + idx) = w;
}

// ---------------------------------------------------------------------------
// bf16 GEMM, m97 structure: 128x128 tile, BK=64, 4 waves (each 64x64 =
// 4x4 fragments of 16x16x32 MFMA), global_load_lds width-16 staging.
// A: [M,K] row-major bf16 (x).  Bw: [N,K] row-major bf16 (ternary weights).
// out = FINAL ? acc*scale[n]+bias[n] (fp32) : relu(acc*scale[n]+bias[n]) (bf16)
// M,N divisible by 128; K divisible by 64.
// ---------------------------------------------------------------------------
template<bool FINAL>
__global__ __launch_bounds__(256) void gemm_bt_k(
    const unsigned short* __restrict__ A,
    const unsigned short* __restrict__ Bw,
    const float* __restrict__ scale,
    const float* __restrict__ bias,
    void* __restrict__ Cout,
    int M, int N, int K)
{
  __shared__ unsigned short As[128 * 64];
  __shared__ unsigned short Bs[128 * 64];

  const int tid  = threadIdx.x;
  const int lane = tid & 63;
  const int wid  = tid >> 6;   // 0..3
  const int wm   = wid >> 1;   // 0..1
  const int wn   = wid & 1;    // 0..1

  const int mBase = blockIdx.y * 128;
  const int nBase = blockIdx.x * 128;

  // staging map: chunk c (0..15) = 1024 B = 8 rows of 64 bf16.
  // lane l writes lds byte c*1024 + l*16 -> row c*8 + (l>>3), k (l&7)*8
  const int srow = lane >> 3;
  const int skel = (lane & 7) * 8;

  f32x4 acc[4][4];
  #pragma unroll
  for (int i = 0; i < 4; ++i)
    #pragma unroll
    for (int j = 0; j < 4; ++j)
      acc[i][j] = (f32x4){0.f, 0.f, 0.f, 0.f};

  for (int k0 = 0; k0 < K; k0 += 64) {
    #pragma unroll
    for (int j = 0; j < 4; ++j) {
      const int c = wid * 4 + j;
      const int row = c * 8 + srow;
      load_lds16(A  + (size_t)(mBase + row) * K + (k0 + skel), As + c * 512);
      load_lds16(Bw + (size_t)(nBase + row) * K + (k0 + skel), Bs + c * 512);
    }
    __syncthreads();  // compiler emits vmcnt(0) drain before s_barrier

    #pragma unroll
    for (int s = 0; s < 2; ++s) {
      const int kk = s * 32 + (lane >> 4) * 8;
      bf16x8 af[4], bfr[4];
      #pragma unroll
      for (int i = 0; i < 4; ++i)
        af[i] = *(const bf16x8*)(As + (wm * 64 + i * 16 + (lane & 15)) * 64 + kk);
      #pragma unroll
      for (int j = 0; j < 4; ++j)
        bfr[j] = *(const bf16x8*)(Bs + (wn * 64 + j * 16 + (lane & 15)) * 64 + kk);
      #pragma unroll
      for (int i = 0; i < 4; ++i)
        #pragma unroll
        for (int j = 0; j < 4; ++j)
          acc[i][j] = __builtin_amdgcn_mfma_f32_16x16x32_bf16(af[i], bfr[j], acc[i][j], 0, 0, 0);
    }
    __syncthreads();
  }

  // epilogue: C/D layout col = lane&15, row = (lane>>4)*4 + reg  [m89-verified]
  const int lr = lane >> 4;
  const int lc = lane & 15;
  #pragma unroll
  for (int j = 0; j < 4; ++j) {
    const int col = nBase + wn * 64 + j * 16 + lc;
    const float sc = scale[col];
    const float bs = bias[col];
    #pragma unroll
    for (int i = 0; i < 4; ++i) {
      const int r0 = mBase + wm * 64 + i * 16 + lr * 4;
      #pragma unroll
      for (int r = 0; r < 4; ++r) {
        float vv = acc[i][j][r] * sc + bs;
        if (!FINAL) {
          vv = fmaxf(vv, 0.0f);
          ((unsigned short*)Cout)[(size_t)(r0 + r) * N + col] = f2bf(vv);
        } else {
          ((float*)Cout)[(size_t)(r0 + r) * N + col] = vv;
        }
      }
    }
  }
}

// ---------------------------------------------------------------------------
extern "C" void kernel_launch(void* const* d_in, const int* in_sizes, int n_in,
                              void* d_out, int out_size, void* d_ws, size_t ws_size,
                              hipStream_t stream) {
  const int V = 32000, H = 2048, L = 4, M = 4096;  // M = B*S
  const int*   ids         = (const int*)d_in[0];
  const float* emb         = (const float*)d_in[1];
  const void*  layer_wq    = d_in[2];
  const float* layer_scale = (const float*)d_in[3];
  const float* layer_bias  = (const float*)d_in[4];
  const void*  out_wq      = d_in[5];
  const float* out_scale   = (const float*)d_in[6];
  const float* out_bias    = (const float*)d_in[7];
  float* out = (float*)d_out;

  // ws layout (bytes):
  //   xA: 0 .. 16 MiB      xB: 16 .. 32 MiB
  //   lw (L*H*H bf16): 32 MiB .. 64 MiB
  //   ow (V*H bf16):   64 MiB .. +131 MB
  //   flag: 4 B after that                (total ~189 MB)
  char* ws = (char*)d_ws;
  const size_t xBytes = (size_t)M * H * 2;
  unsigned short* xA = (unsigned short*)(ws);
  unsigned short* xB = (unsigned short*)(ws + xBytes);
  unsigned short* lw = (unsigned short*)(ws + 2 * xBytes);
  unsigned short* ow = (unsigned short*)(ws + 2 * xBytes + (size_t)L * H * H * 2);
  int* flag = (int*)(ws + 2 * xBytes + (size_t)L * H * H * 2 + (size_t)V * H * 2);

  detect_dtype_k<<<1, 256, 0, stream>>>((const int*)layer_wq, flag);
  gather_emb_k<<<M, 256, 0, stream>>>(ids, emb, xA);
  convert_w_k<<<(L * H * H) / 2048, 256, 0, stream>>>(layer_wq, lw, flag);
  convert_w_k<<<(V * H) / 2048, 256, 0, stream>>>(out_wq, ow, flag);

  dim3 blk(256);
  dim3 gh(H / 128, M / 128);        // (16, 32)
  unsigned short* xin = xA;
  unsigned short* xout = xB;
  for (int i = 0; i < L; ++i) {
    gemm_bt_k<false><<<gh, blk, 0, stream>>>(xin, lw + (size_t)i * H * H,
                                             layer_scale + i * H, layer_bias + i * H,
                                             xout, M, H, H);
    unsigned short* t = xin; xin = xout; xout = t;
  }
  dim3 go(V / 128, M / 128);        // (250, 32)
  gemm_bt_k<true><<<go, blk, 0, stream>>>(xin, ow, out_scale, out_bias, out, M, V, H);
}

// Round 2
// 1072.985 us; speedup vs baseline: 1.0583x; 1.0583x over previous
//
#include <hip/hip_runtime.h>
#include <hip/hip_bf16.h>
#include <stdint.h>
#include <stddef.h>

#define GLOBAL_AS __attribute__((address_space(1)))
#define LDS_AS __attribute__((address_space(3)))

typedef __attribute__((ext_vector_type(4))) float f32x4;
typedef __attribute__((ext_vector_type(8))) short bf16x8;

__device__ __forceinline__ unsigned short f2bf(float f) {
  unsigned u = __float_as_uint(f);
  u += 0x7FFFu + ((u >> 16) & 1u);   // round-to-nearest-even
  return (unsigned short)(u >> 16);
}

__device__ __forceinline__ void load_lds16(const void* g, void* l) {
  __builtin_amdgcn_global_load_lds((const GLOBAL_AS void*)g, (LDS_AS void*)l, 16, 0, 0);
}

// ---------------------------------------------------------------------------
// Detect int8 vs int32 storage of the ternary weights (see round-0 notes).
// ---------------------------------------------------------------------------
__global__ __launch_bounds__(256) void detect_dtype_k(const int* __restrict__ w,
                                                      int* __restrict__ flag) {
  __shared__ int bad;
  if (threadIdx.x == 0) bad = 0;
  __syncthreads();
  int b = 0;
  for (int i = threadIdx.x; i < 4096; i += 256) {
    int v = w[i];
    if (v < -1 || v > 1) b = 1;
  }
  if (b) bad = 1;
  __syncthreads();
  if (threadIdx.x == 0) *flag = bad ? 0 : 1;
}

// ---------------------------------------------------------------------------
// x0[t][h] = bf16(emb[ids[t]][h])
// ---------------------------------------------------------------------------
__global__ __launch_bounds__(256) void gather_emb_k(const int* __restrict__ ids,
                                                    const float* __restrict__ emb,
                                                    unsigned short* __restrict__ x) {
  const int t = blockIdx.x;
  const int row = ids[t];
  const float4* src = (const float4*)(emb + (size_t)row * 2048);
  const int e = threadIdx.x;
  float4 a = src[e * 2], b = src[e * 2 + 1];
  uint4 o;
  o.x = f2bf(a.x) | ((unsigned)f2bf(a.y) << 16);
  o.y = f2bf(a.z) | ((unsigned)f2bf(a.w) << 16);
  o.z = f2bf(b.x) | ((unsigned)f2bf(b.y) << 16);
  o.w = f2bf(b.z) | ((unsigned)f2bf(b.w) << 16);
  *(uint4*)(x + (size_t)t * 2048 + e * 8) = o;
}

// ---------------------------------------------------------------------------
// ternary int8-or-int32 -> bf16
// ---------------------------------------------------------------------------
__global__ __launch_bounds__(256) void convert_w_k(const void* __restrict__ src,
                                                   unsigned short* __restrict__ dst,
                                                   const int* __restrict__ flag) {
  const long long idx = ((long long)blockIdx.x * 256 + threadIdx.x) * 8;
  int v[8];
  if (*flag) {
    const int* s = (const int*)src + idx;
    const int4 a = *(const int4*)s;
    const int4 b = *(const int4*)(s + 4);
    v[0] = a.x; v[1] = a.y; v[2] = a.z; v[3] = a.w;
    v[4] = b.x; v[5] = b.y; v[6] = b.z; v[7] = b.w;
  } else {
    const uint2 u = *(const uint2*)((const char*)src + idx);
    v[0] = (char)(u.x); v[1] = (char)(u.x >> 8); v[2] = (char)(u.x >> 16); v[3] = (char)(u.x >> 24);
    v[4] = (char)(u.y); v[5] = (char)(u.y >> 8); v[6] = (char)(u.y >> 16); v[7] = (char)(u.y >> 24);
  }
  unsigned short o[8];
  #pragma unroll
  for (int k = 0; k < 8; ++k)
    o[k] = (v[k] == 0) ? 0 : ((v[k] > 0) ? 0x3F80 : 0xBF80);
  uint4 w;
  w.x = o[0] | ((unsigned)o[1] << 16);
  w.y = o[2] | ((unsigned)o[3] << 16);
  w.z = o[4] | ((unsigned)o[5] << 16);
  w.w = o[6] | ((unsigned)o[7] << 16);
  *(uint4*)(dst + idx) = w;
}

// ---------------------------------------------------------------------------
// Hidden-layer GEMM: m97-structure 128x128 tile (unchanged, passing).
// ---------------------------------------------------------------------------
__global__ __launch_bounds__(256) void gemm_bt_k(
    const unsigned short* __restrict__ A,
    const unsigned short* __restrict__ Bw,
    const float* __restrict__ scale,
    const float* __restrict__ bias,
    unsigned short* __restrict__ Cout,
    int M, int N, int K)
{
  __shared__ unsigned short As[128 * 64];
  __shared__ unsigned short Bs[128 * 64];

  const int tid  = threadIdx.x;
  const int lane = tid & 63;
  const int wid  = tid >> 6;
  const int wm   = wid >> 1;
  const int wn   = wid & 1;

  const int mBase = blockIdx.y * 128;
  const int nBase = blockIdx.x * 128;

  const int srow = lane >> 3;
  const int skel = (lane & 7) * 8;

  f32x4 acc[4][4];
  #pragma unroll
  for (int i = 0; i < 4; ++i)
    #pragma unroll
    for (int j = 0; j < 4; ++j)
      acc[i][j] = (f32x4){0.f, 0.f, 0.f, 0.f};

  for (int k0 = 0; k0 < K; k0 += 64) {
    #pragma unroll
    for (int j = 0; j < 4; ++j) {
      const int c = wid * 4 + j;
      const int row = c * 8 + srow;
      load_lds16(A  + (size_t)(mBase + row) * K + (k0 + skel), As + c * 512);
      load_lds16(Bw + (size_t)(nBase + row) * K + (k0 + skel), Bs + c * 512);
    }
    __syncthreads();

    #pragma unroll
    for (int s = 0; s < 2; ++s) {
      const int kk = s * 32 + (lane >> 4) * 8;
      bf16x8 af[4], bfr[4];
      #pragma unroll
      for (int i = 0; i < 4; ++i)
        af[i] = *(const bf16x8*)(As + (wm * 64 + i * 16 + (lane & 15)) * 64 + kk);
      #pragma unroll
      for (int j = 0; j < 4; ++j)
        bfr[j] = *(const bf16x8*)(Bs + (wn * 64 + j * 16 + (lane & 15)) * 64 + kk);
      #pragma unroll
      for (int i = 0; i < 4; ++i)
        #pragma unroll
        for (int j = 0; j < 4; ++j)
          acc[i][j] = __builtin_amdgcn_mfma_f32_16x16x32_bf16(af[i], bfr[j], acc[i][j], 0, 0, 0);
    }
    __syncthreads();
  }

  const int lr = lane >> 4;
  const int lc = lane & 15;
  #pragma unroll
  for (int j = 0; j < 4; ++j) {
    const int col = nBase + wn * 64 + j * 16 + lc;
    const float sc = scale[col];
    const float bs = bias[col];
    #pragma unroll
    for (int i = 0; i < 4; ++i) {
      const int r0 = mBase + wm * 64 + i * 16 + lr * 4;
      #pragma unroll
      for (int r = 0; r < 4; ++r) {
        float vv = fmaxf(acc[i][j][r] * sc + bs, 0.0f);
        Cout[(size_t)(r0 + r) * N + col] = f2bf(vv);
      }
    }
  }
}

// ---------------------------------------------------------------------------
// Final GEMM: 256x256 tile, BK=64, 8 waves (2M x 4N), double-buffered LDS,
// counted vmcnt(8) pipeline (2 K-tiles in flight), XOR-swizzled LDS via
// pre-swizzled global source (rule #21), setprio around MFMA phases,
// m-fastest + bijective XCD block mapping for B L2/L3 residency.
// M=4096, N=32000, K=2048.  Grid = 2000 blocks x 512 threads.
// ---------------------------------------------------------------------------
__global__ __launch_bounds__(512) void gemm256_final_k(
    const unsigned short* __restrict__ A,
    const unsigned short* __restrict__ Bw,
    const float* __restrict__ scale,
    const float* __restrict__ bias,
    float* __restrict__ C,
    int M, int N, int K)
{
  __shared__ unsigned short As[2][256 * 64];
  __shared__ unsigned short Bs[2][256 * 64];

  const int tid  = threadIdx.x;
  const int lane = tid & 63;
  const int wid  = tid >> 6;   // 0..7
  const int wm   = wid >> 2;   // 0..1  (128-row half)
  const int wn   = wid & 3;    // 0..3  (64-col quarter)

  // bijective XCD swizzle (nwg % 8 == 0: 2000 = 8*250), then m-fastest
  const int q    = gridDim.x >> 3;
  const int wgid = (blockIdx.x & 7) * q + (blockIdx.x >> 3);
  const int mBase = (wgid & 15) << 8;   // M/256 = 16 m-tiles, fastest
  const int nBase = (wgid >> 4) << 8;

  // staging: chunk c (0..31) = 8 rows x 64 cols = 1024 B, one wave-instr.
  // lane l -> LDS row R=l>>3, granule l&7 (linear dest); source granule
  // pre-swizzled (l&7)^R so that read-side XOR recovers linear data.
  const int R   = lane >> 3;
  const int gsw = ((lane & 7) ^ R) * 8;

  auto stage = [&](int tk, int buf) {
    const int kcol = tk * 64 + gsw;
    #pragma unroll
    for (int j = 0; j < 4; ++j) {
      const int c = wid * 4 + j;
      const int grow = c * 8 + R;
      load_lds16(A  + (size_t)(mBase + grow) * K + kcol, &As[buf][c * 512]);
      load_lds16(Bw + (size_t)(nBase + grow) * K + kcol, &Bs[buf][c * 512]);
    }
  };

  f32x4 acc[8][4];
  #pragma unroll
  for (int i = 0; i < 8; ++i)
    #pragma unroll
    for (int j = 0; j < 4; ++j)
      acc[i][j] = (f32x4){0.f, 0.f, 0.f, 0.f};

  stage(0, 0);
  stage(1, 1);

  const int nt = K >> 6;   // 32
  for (int t = 0; t < nt; ++t) {
    const int curb = t & 1;
    // wait for buf[curb]'s 8 loads; the next tile's 8 stay in flight
    if (t < nt - 1) asm volatile("s_waitcnt vmcnt(8)" ::: "memory");
    else            asm volatile("s_waitcnt vmcnt(0)" ::: "memory");
    __builtin_amdgcn_s_barrier();
    __builtin_amdgcn_sched_barrier(0);

    const unsigned short* asb = &As[curb][0];
    const unsigned short* bsb = &Bs[curb][0];

    // B fragments for the whole tile (8 reads), held in regs
    bf16x8 bfr[4][2];
    #pragma unroll
    for (int j = 0; j < 4; ++j)
      #pragma unroll
      for (int s = 0; s < 2; ++s) {
        const int row = wn * 64 + j * 16 + (lane & 15);
        const int kk  = s * 32 + (lane >> 4) * 8;
        bfr[j][s] = *(const bf16x8*)(bsb + row * 64 + (kk ^ ((row & 7) * 8)));
      }

    // 4 phases x 16 MFMA, A fragments loaded per phase
    #pragma unroll
    for (int ip = 0; ip < 4; ++ip) {
      bf16x8 af[2][2];
      #pragma unroll
      for (int ii = 0; ii < 2; ++ii)
        #pragma unroll
        for (int s = 0; s < 2; ++s) {
          const int row = wm * 128 + (ip * 2 + ii) * 16 + (lane & 15);
          const int kk  = s * 32 + (lane >> 4) * 8;
          af[ii][s] = *(const bf16x8*)(asb + row * 64 + (kk ^ ((row & 7) * 8)));
        }
      __builtin_amdgcn_s_setprio(1);
      #pragma unroll
      for (int ii = 0; ii < 2; ++ii)
        #pragma unroll
        for (int j = 0; j < 4; ++j) {
          acc[ip * 2 + ii][j] = __builtin_amdgcn_mfma_f32_16x16x32_bf16(
              af[ii][0], bfr[j][0], acc[ip * 2 + ii][j], 0, 0, 0);
          acc[ip * 2 + ii][j] = __builtin_amdgcn_mfma_f32_16x16x32_bf16(
              af[ii][1], bfr[j][1], acc[ip * 2 + ii][j], 0, 0, 0);
        }
      __builtin_amdgcn_s_setprio(0);
    }

    __builtin_amdgcn_sched_barrier(0);
    __builtin_amdgcn_s_barrier();           // all waves done reading buf[curb]
    if (t + 2 < nt) stage(t + 2, curb);     // refill it two tiles ahead
  }

  // epilogue: C/D layout col = lane&15, row = (lane>>4)*4 + reg
  const int lr = lane >> 4;
  const int lc = lane & 15;
  #pragma unroll
  for (int j = 0; j < 4; ++j) {
    const int col = nBase + wn * 64 + j * 16 + lc;
    const float sc = scale[col];
    const float bs = bias[col];
    #pragma unroll
    for (int i = 0; i < 8; ++i) {
      const int r0 = mBase + wm * 128 + i * 16 + lr * 4;
      #pragma unroll
      for (int r = 0; r < 4; ++r)
        C[(size_t)(r0 + r) * N + col] = acc[i][j][r] * sc + bs;
    }
  }
}

// ---------------------------------------------------------------------------
extern "C" void kernel_launch(void* const* d_in, const int* in_sizes, int n_in,
                              void* d_out, int out_size, void* d_ws, size_t ws_size,
                              hipStream_t stream) {
  const int V = 32000, H = 2048, L = 4, M = 4096;
  const int*   ids         = (const int*)d_in[0];
  const float* emb         = (const float*)d_in[1];
  const void*  layer_wq    = d_in[2];
  const float* layer_scale = (const float*)d_in[3];
  const float* layer_bias  = (const float*)d_in[4];
  const void*  out_wq      = d_in[5];
  const float* out_scale   = (const float*)d_in[6];
  const float* out_bias    = (const float*)d_in[7];
  float* out = (float*)d_out;

  char* ws = (char*)d_ws;
  const size_t xBytes = (size_t)M * H * 2;
  unsigned short* xA = (unsigned short*)(ws);
  unsigned short* xB = (unsigned short*)(ws + xBytes);
  unsigned short* lw = (unsigned short*)(ws + 2 * xBytes);
  unsigned short* ow = (unsigned short*)(ws + 2 * xBytes + (size_t)L * H * H * 2);
  int* flag = (int*)(ws + 2 * xBytes + (size_t)L * H * H * 2 + (size_t)V * H * 2);

  detect_dtype_k<<<1, 256, 0, stream>>>((const int*)layer_wq, flag);
  gather_emb_k<<<M, 256, 0, stream>>>(ids, emb, xA);
  convert_w_k<<<(L * H * H) / 2048, 256, 0, stream>>>(layer_wq, lw, flag);
  convert_w_k<<<(V * H) / 2048, 256, 0, stream>>>(out_wq, ow, flag);

  dim3 blk(256);
  dim3 gh(H / 128, M / 128);
  unsigned short* xin = xA;
  unsigned short* xout = xB;
  for (int i = 0; i < L; ++i) {
    gemm_bt_k<<<gh, blk, 0, stream>>>(xin, lw + (size_t)i * H * H,
                                      layer_scale + i * H, layer_bias + i * H,
                                      xout, M, H, H);
    unsigned short* t = xin; xin = xout; xout = t;
  }
  // final: 256^2 tiles -> (M/256)*(V/256) = 16*125 = 2000 blocks
  gemm256_final_k<<<dim3(2000), dim3(512), 0, stream>>>(
      xin, ow, out_scale, out_bias, out, M, V, H);
}

// Round 3
// 1066.152 us; speedup vs baseline: 1.0651x; 1.0064x over previous
//
#include <hip/hip_runtime.h>
#include <hip/hip_bf16.h>
#include <stdint.h>
#include <stddef.h>

#define GLOBAL_AS __attribute__((address_space(1)))
#define LDS_AS __attribute__((address_space(3)))

typedef __attribute__((ext_vector_type(4))) float f32x4;
typedef __attribute__((ext_vector_type(8))) short bf16x8;

__device__ __forceinline__ unsigned short f2bf(float f) {
  unsigned u = __float_as_uint(f);
  u += 0x7FFFu + ((u >> 16) & 1u);   // round-to-nearest-even
  return (unsigned short)(u >> 16);
}

__device__ __forceinline__ void load_lds16(const void* g, void* l) {
  __builtin_amdgcn_global_load_lds((const GLOBAL_AS void*)g, (LDS_AS void*)l, 16, 0, 0);
}

// ---------------------------------------------------------------------------
// Detect int8 vs int32 storage of the ternary weights (see round-0 notes).
// ---------------------------------------------------------------------------
__global__ __launch_bounds__(256) void detect_dtype_k(const int* __restrict__ w,
                                                      int* __restrict__ flag) {
  __shared__ int bad;
  if (threadIdx.x == 0) bad = 0;
  __syncthreads();
  int b = 0;
  for (int i = threadIdx.x; i < 4096; i += 256) {
    int v = w[i];
    if (v < -1 || v > 1) b = 1;
  }
  if (b) bad = 1;
  __syncthreads();
  if (threadIdx.x == 0) *flag = bad ? 0 : 1;
}

// ---------------------------------------------------------------------------
// x0[t][h] = bf16(emb[ids[t]][h])
// ---------------------------------------------------------------------------
__global__ __launch_bounds__(256) void gather_emb_k(const int* __restrict__ ids,
                                                    const float* __restrict__ emb,
                                                    unsigned short* __restrict__ x) {
  const int t = blockIdx.x;
  const int row = ids[t];
  const float4* src = (const float4*)(emb + (size_t)row * 2048);
  const int e = threadIdx.x;
  float4 a = src[e * 2], b = src[e * 2 + 1];
  uint4 o;
  o.x = f2bf(a.x) | ((unsigned)f2bf(a.y) << 16);
  o.y = f2bf(a.z) | ((unsigned)f2bf(a.w) << 16);
  o.z = f2bf(b.x) | ((unsigned)f2bf(b.y) << 16);
  o.w = f2bf(b.z) | ((unsigned)f2bf(b.w) << 16);
  *(uint4*)(x + (size_t)t * 2048 + e * 8) = o;
}

// ---------------------------------------------------------------------------
// ternary int8-or-int32 -> bf16
// ---------------------------------------------------------------------------
__global__ __launch_bounds__(256) void convert_w_k(const void* __restrict__ src,
                                                   unsigned short* __restrict__ dst,
                                                   const int* __restrict__ flag) {
  const long long idx = ((long long)blockIdx.x * 256 + threadIdx.x) * 8;
  int v[8];
  if (*flag) {
    const int* s = (const int*)src + idx;
    const int4 a = *(const int4*)s;
    const int4 b = *(const int4*)(s + 4);
    v[0] = a.x; v[1] = a.y; v[2] = a.z; v[3] = a.w;
    v[4] = b.x; v[5] = b.y; v[6] = b.z; v[7] = b.w;
  } else {
    const uint2 u = *(const uint2*)((const char*)src + idx);
    v[0] = (char)(u.x); v[1] = (char)(u.x >> 8); v[2] = (char)(u.x >> 16); v[3] = (char)(u.x >> 24);
    v[4] = (char)(u.y); v[5] = (char)(u.y >> 8); v[6] = (char)(u.y >> 16); v[7] = (char)(u.y >> 24);
  }
  unsigned short o[8];
  #pragma unroll
  for (int k = 0; k < 8; ++k)
    o[k] = (v[k] == 0) ? 0 : ((v[k] > 0) ? 0x3F80 : 0xBF80);
  uint4 w;
  w.x = o[0] | ((unsigned)o[1] << 16);
  w.y = o[2] | ((unsigned)o[3] << 16);
  w.z = o[4] | ((unsigned)o[5] << 16);
  w.w = o[6] | ((unsigned)o[7] << 16);
  *(uint4*)(dst + idx) = w;
}

// ---------------------------------------------------------------------------
// Hidden-layer GEMM: m97-structure 128x128 tile (unchanged, passing).
// ---------------------------------------------------------------------------
__global__ __launch_bounds__(256) void gemm_bt_k(
    const unsigned short* __restrict__ A,
    const unsigned short* __restrict__ Bw,
    const float* __restrict__ scale,
    const float* __restrict__ bias,
    unsigned short* __restrict__ Cout,
    int M, int N, int K)
{
  __shared__ unsigned short As[128 * 64];
  __shared__ unsigned short Bs[128 * 64];

  const int tid  = threadIdx.x;
  const int lane = tid & 63;
  const int wid  = tid >> 6;
  const int wm   = wid >> 1;
  const int wn   = wid & 1;

  const int mBase = blockIdx.y * 128;
  const int nBase = blockIdx.x * 128;

  const int srow = lane >> 3;
  const int skel = (lane & 7) * 8;

  f32x4 acc[4][4];
  #pragma unroll
  for (int i = 0; i < 4; ++i)
    #pragma unroll
    for (int j = 0; j < 4; ++j)
      acc[i][j] = (f32x4){0.f, 0.f, 0.f, 0.f};

  for (int k0 = 0; k0 < K; k0 += 64) {
    #pragma unroll
    for (int j = 0; j < 4; ++j) {
      const int c = wid * 4 + j;
      const int row = c * 8 + srow;
      load_lds16(A  + (size_t)(mBase + row) * K + (k0 + skel), As + c * 512);
      load_lds16(Bw + (size_t)(nBase + row) * K + (k0 + skel), Bs + c * 512);
    }
    __syncthreads();

    #pragma unroll
    for (int s = 0; s < 2; ++s) {
      const int kk = s * 32 + (lane >> 4) * 8;
      bf16x8 af[4], bfr[4];
      #pragma unroll
      for (int i = 0; i < 4; ++i)
        af[i] = *(const bf16x8*)(As + (wm * 64 + i * 16 + (lane & 15)) * 64 + kk);
      #pragma unroll
      for (int j = 0; j < 4; ++j)
        bfr[j] = *(const bf16x8*)(Bs + (wn * 64 + j * 16 + (lane & 15)) * 64 + kk);
      #pragma unroll
      for (int i = 0; i < 4; ++i)
        #pragma unroll
        for (int j = 0; j < 4; ++j)
          acc[i][j] = __builtin_amdgcn_mfma_f32_16x16x32_bf16(af[i], bfr[j], acc[i][j], 0, 0, 0);
    }
    __syncthreads();
  }

  const int lr = lane >> 4;
  const int lc = lane & 15;
  #pragma unroll
  for (int j = 0; j < 4; ++j) {
    const int col = nBase + wn * 64 + j * 16 + lc;
    const float sc = scale[col];
    const float bs = bias[col];
    #pragma unroll
    for (int i = 0; i < 4; ++i) {
      const int r0 = mBase + wm * 64 + i * 16 + lr * 4;
      #pragma unroll
      for (int r = 0; r < 4; ++r) {
        float vv = fmaxf(acc[i][j][r] * sc + bs, 0.0f);
        Cout[(size_t)(r0 + r) * N + col] = f2bf(vv);
      }
    }
  }
}

// ---------------------------------------------------------------------------
// Final GEMM, 8-phase m201-style schedule:
// 256x256 tile, BK=64, 8 waves (2M x 4N), 2 K-tile LDS buffers (128 KiB),
// 4 phases per K-tile: {4-12 ds_read_b128 || 1 half-tile stage (2x
// global_load_lds) -> s_barrier -> lgkmcnt(0) -> sched_barrier ->
// setprio(1) 16 MFMA setprio(0)} ; counted vmcnt(4) once per K-tile
// (2 half-tiles stay in flight across barriers, never drained mid-loop).
// Stage slotting: A(t+1) at phases 0,1 ; B(t+2) at phases 2,3
// (A slots free after prior tile's phase 3; B slots free after phase 0).
// LDS XOR swizzle via pre-swizzled global source + swizzled ds_read (r21).
// ---------------------------------------------------------------------------
__global__ __launch_bounds__(512) void gemm256_final_k(
    const unsigned short* __restrict__ A,
    const unsigned short* __restrict__ Bw,
    const float* __restrict__ scale,
    const float* __restrict__ bias,
    float* __restrict__ C,
    int M, int N, int K)
{
  // per buffer: 256 rows x 64 cols ushort = 16384 elems; A half = 8192 elems
  __shared__ unsigned short As[2 * 16384];
  __shared__ unsigned short Bs[2 * 16384];

  const int tid  = threadIdx.x;
  const int lane = tid & 63;
  const int wid  = tid >> 6;   // 0..7
  const int wm   = wid >> 2;   // 0..1  (128-row half)
  const int wn   = wid & 3;    // 0..3  (64-col quarter)
  const int l15  = lane & 15;
  const int l4   = lane >> 4;

  // bijective XCD swizzle (2000 = 8*250), then m-fastest for B reuse
  const int q    = gridDim.x >> 3;
  const int wgid = (blockIdx.x & 7) * q + (blockIdx.x >> 3);
  const int mBase = (wgid & 15) << 8;
  const int nBase = (wgid >> 4) << 8;

  // staging: lane l of wave w, instr j covers LDS row j*64+w*8+(l>>3),
  // granule l&7 (linear dest); global source granule pre-XORed with row&7.
  const int gsw = ((lane & 7) ^ (lane >> 3)) * 8;

  auto stage_half = [&](const unsigned short* __restrict__ G, int growBase,
                        int kcol, unsigned short* ldsHalf) {
    #pragma unroll
    for (int j = 0; j < 2; ++j)
      load_lds16(G + (size_t)(growBase + j * 64 + wid * 8 + (lane >> 3)) * K + kcol + gsw,
                 ldsHalf + j * 4096 + wid * 512);
  };

  f32x4 acc[8][4];
  #pragma unroll
  for (int i = 0; i < 8; ++i)
    #pragma unroll
    for (int j = 0; j < 4; ++j)
      acc[i][j] = (f32x4){0.f, 0.f, 0.f, 0.f};

  const int nt = K >> 6;   // 32 K-tiles

  // prologue: fully stage tiles 0 and 1 (8 half-tiles, 16 instrs/wave)
  stage_half(A,  mBase,       0,  As);
  stage_half(A,  mBase + 128, 0,  As + 8192);
  stage_half(Bw, nBase,       0,  Bs);
  stage_half(Bw, nBase + 128, 0,  Bs + 8192);
  stage_half(A,  mBase,       64, As + 16384);
  stage_half(A,  mBase + 128, 64, As + 16384 + 8192);
  stage_half(Bw, nBase,       64, Bs + 16384);
  stage_half(Bw, nBase + 128, 64, Bs + 16384 + 8192);
  asm volatile("s_waitcnt vmcnt(8)" ::: "memory");   // tile 0 landed; tile 1 in flight
  __builtin_amdgcn_s_barrier();

  bf16x8 bfr[4][2];   // B fragments, live across the 4 phases of a tile

  for (int t = 0; t < nt; ++t) {
    const unsigned short* asb = As + (t & 1) * 16384;
    const unsigned short* bsb = Bs + (t & 1) * 16384;

    #pragma unroll
    for (int ip = 0; ip < 4; ++ip) {
      // ---- ds-loads for this phase (A pair; B full set on phase 0) ----
      bf16x8 af[2][2];
      #pragma unroll
      for (int ii = 0; ii < 2; ++ii)
        #pragma unroll
        for (int s = 0; s < 2; ++s) {
          const int rh = (ip * 2 + ii) * 16 + l15;      // row within A-half wm
          const int gg = s * 4 + l4;                    // 16B granule index
          af[ii][s] = *(const bf16x8*)(asb + wm * 8192 + rh * 64 + ((gg ^ (rh & 7)) * 8));
        }
      if (ip == 0) {
        #pragma unroll
        for (int j = 0; j < 4; ++j)
          #pragma unroll
          for (int s = 0; s < 2; ++s) {
            const int br = wn * 64 + j * 16 + l15;      // row in 256-row B tile
            const int rh = br & 127;
            const int gg = s * 4 + l4;
            bfr[j][s] = *(const bf16x8*)(bsb + (br >> 7) * 8192 + rh * 64 + ((gg ^ (rh & 7)) * 8));
          }
      }

      // ---- stage one half-tile (2 x global_load_lds per wave) ----
      if (ip == 0) { if (t >= 1 && t + 1 < nt)
        stage_half(A,  mBase,       (t + 1) * 64, As + ((t + 1) & 1) * 16384); }
      if (ip == 1) { if (t >= 1 && t + 1 < nt)
        stage_half(A,  mBase + 128, (t + 1) * 64, As + ((t + 1) & 1) * 16384 + 8192); }
      if (ip == 2) { if (t + 2 < nt)
        stage_half(Bw, nBase,       (t + 2) * 64, Bs + (t & 1) * 16384); }
      if (ip == 3) { if (t + 2 < nt)
        stage_half(Bw, nBase + 128, (t + 2) * 64, Bs + (t & 1) * 16384 + 8192); }

      __builtin_amdgcn_s_barrier();
      asm volatile("s_waitcnt lgkmcnt(0)" ::: "memory");
      __builtin_amdgcn_sched_barrier(0);

      __builtin_amdgcn_s_setprio(1);
      #pragma unroll
      for (int ii = 0; ii < 2; ++ii)
        #pragma unroll
        for (int j = 0; j < 4; ++j) {
          acc[ip * 2 + ii][j] = __builtin_amdgcn_mfma_f32_16x16x32_bf16(
              af[ii][0], bfr[j][0], acc[ip * 2 + ii][j], 0, 0, 0);
          acc[ip * 2 + ii][j] = __builtin_amdgcn_mfma_f32_16x16x32_bf16(
              af[ii][1], bfr[j][1], acc[ip * 2 + ii][j], 0, 0, 0);
        }
      __builtin_amdgcn_s_setprio(0);
      __builtin_amdgcn_sched_barrier(0);

      // counted wait once per K-tile: tile t+1's 4 halves complete, the
      // 2 B(t+2) halves (4 instrs) stay in flight across the barrier.
      if (ip == 3) {
        if (t + 2 < nt) asm volatile("s_waitcnt vmcnt(4)" ::: "memory");
        else            asm volatile("s_waitcnt vmcnt(0)" ::: "memory");
      }
      __builtin_amdgcn_s_barrier();
    }
  }

  // epilogue: C/D layout col = lane&15, row = (lane>>4)*4 + reg
  const int lr = l4;
  const int lc = l15;
  #pragma unroll
  for (int j = 0; j < 4; ++j) {
    const int col = nBase + wn * 64 + j * 16 + lc;
    const float sc = scale[col];
    const float bs = bias[col];
    #pragma unroll
    for (int i = 0; i < 8; ++i) {
      const int r0 = mBase + wm * 128 + i * 16 + lr * 4;
      #pragma unroll
      for (int r = 0; r < 4; ++r)
        C[(size_t)(r0 + r) * N + col] = acc[i][j][r] * sc + bs;
    }
  }
}

// ---------------------------------------------------------------------------
extern "C" void kernel_launch(void* const* d_in, const int* in_sizes, int n_in,
                              void* d_out, int out_size, void* d_ws, size_t ws_size,
                              hipStream_t stream) {
  const int V = 32000, H = 2048, L = 4, M = 4096;
  const int*   ids         = (const int*)d_in[0];
  const float* emb         = (const float*)d_in[1];
  const void*  layer_wq    = d_in[2];
  const float* layer_scale = (const float*)d_in[3];
  const float* layer_bias  = (const float*)d_in[4];
  const void*  out_wq      = d_in[5];
  const float* out_scale   = (const float*)d_in[6];
  const float* out_bias    = (const float*)d_in[7];
  float* out = (float*)d_out;

  char* ws = (char*)d_ws;
  const size_t xBytes = (size_t)M * H * 2;
  unsigned short* xA = (unsigned short*)(ws);
  unsigned short* xB = (unsigned short*)(ws + xBytes);
  unsigned short* lw = (unsigned short*)(ws + 2 * xBytes);
  unsigned short* ow = (unsigned short*)(ws + 2 * xBytes + (size_t)L * H * H * 2);
  int* flag = (int*)(ws + 2 * xBytes + (size_t)L * H * H * 2 + (size_t)V * H * 2);

  detect_dtype_k<<<1, 256, 0, stream>>>((const int*)layer_wq, flag);
  gather_emb_k<<<M, 256, 0, stream>>>(ids, emb, xA);
  convert_w_k<<<(L * H * H) / 2048, 256, 0, stream>>>(layer_wq, lw, flag);
  convert_w_k<<<(V * H) / 2048, 256, 0, stream>>>(out_wq, ow, flag);

  dim3 blk(256);
  dim3 gh(H / 128, M / 128);
  unsigned short* xin = xA;
  unsigned short* xout = xB;
  for (int i = 0; i < L; ++i) {
    gemm_bt_k<<<gh, blk, 0, stream>>>(xin, lw + (size_t)i * H * H,
                                      layer_scale + i * H, layer_bias + i * H,
                                      xout, M, H, H);
    unsigned short* t = xin; xin = xout; xout = t;
  }
  // final: (M/256)*(V/256) = 16*125 = 2000 blocks
  gemm256_final_k<<<dim3(2000), dim3(512), 0, stream>>>(
      xin, ow, out_scale, out_bias, out, M, V, H);
}

// Round 4
// 947.271 us; speedup vs baseline: 1.1988x; 1.1255x over previous
//
#include <hip/hip_runtime.h>
#include <hip/hip_bf16.h>
#include <stdint.h>
#include <stddef.h>

#define GLOBAL_AS __attribute__((address_space(1)))
#define LDS_AS __attribute__((address_space(3)))

typedef __attribute__((ext_vector_type(4))) float f32x4;
typedef __attribute__((ext_vector_type(8))) short bf16x8;

__device__ __forceinline__ unsigned short f2bf(float f) {
  unsigned u = __float_as_uint(f);
  u += 0x7FFFu + ((u >> 16) & 1u);   // round-to-nearest-even
  return (unsigned short)(u >> 16);
}

__device__ __forceinline__ void load_lds16(const void* g, void* l) {
  __builtin_amdgcn_global_load_lds((const GLOBAL_AS void*)g, (LDS_AS void*)l, 16, 0, 0);
}

// ---------------------------------------------------------------------------
// Detect int8 vs int32 storage of the ternary weights (see round-0 notes).
// ---------------------------------------------------------------------------
__global__ __launch_bounds__(256) void detect_dtype_k(const int* __restrict__ w,
                                                      int* __restrict__ flag) {
  __shared__ int bad;
  if (threadIdx.x == 0) bad = 0;
  __syncthreads();
  int b = 0;
  for (int i = threadIdx.x; i < 4096; i += 256) {
    int v = w[i];
    if (v < -1 || v > 1) b = 1;
  }
  if (b) bad = 1;
  __syncthreads();
  if (threadIdx.x == 0) *flag = bad ? 0 : 1;
}

// ---------------------------------------------------------------------------
// x0[t][h] = bf16(emb[ids[t]][h])
// ---------------------------------------------------------------------------
__global__ __launch_bounds__(256) void gather_emb_k(const int* __restrict__ ids,
                                                    const float* __restrict__ emb,
                                                    unsigned short* __restrict__ x) {
  const int t = blockIdx.x;
  const int row = ids[t];
  const float4* src = (const float4*)(emb + (size_t)row * 2048);
  const int e = threadIdx.x;
  float4 a = src[e * 2], b = src[e * 2 + 1];
  uint4 o;
  o.x = f2bf(a.x) | ((unsigned)f2bf(a.y) << 16);
  o.y = f2bf(a.z) | ((unsigned)f2bf(a.w) << 16);
  o.z = f2bf(b.x) | ((unsigned)f2bf(b.y) << 16);
  o.w = f2bf(b.z) | ((unsigned)f2bf(b.w) << 16);
  *(uint4*)(x + (size_t)t * 2048 + e * 8) = o;
}

// ---------------------------------------------------------------------------
// ternary int8-or-int32 -> bf16
// ---------------------------------------------------------------------------
__global__ __launch_bounds__(256) void convert_w_k(const void* __restrict__ src,
                                                   unsigned short* __restrict__ dst,
                                                   const int* __restrict__ flag) {
  const long long idx = ((long long)blockIdx.x * 256 + threadIdx.x) * 8;
  int v[8];
  if (*flag) {
    const int* s = (const int*)src + idx;
    const int4 a = *(const int4*)s;
    const int4 b = *(const int4*)(s + 4);
    v[0] = a.x; v[1] = a.y; v[2] = a.z; v[3] = a.w;
    v[4] = b.x; v[5] = b.y; v[6] = b.z; v[7] = b.w;
  } else {
    const uint2 u = *(const uint2*)((const char*)src + idx);
    v[0] = (char)(u.x); v[1] = (char)(u.x >> 8); v[2] = (char)(u.x >> 16); v[3] = (char)(u.x >> 24);
    v[4] = (char)(u.y); v[5] = (char)(u.y >> 8); v[6] = (char)(u.y >> 16); v[7] = (char)(u.y >> 24);
  }
  unsigned short o[8];
  #pragma unroll
  for (int k = 0; k < 8; ++k)
    o[k] = (v[k] == 0) ? 0 : ((v[k] > 0) ? 0x3F80 : 0xBF80);
  uint4 w;
  w.x = o[0] | ((unsigned)o[1] << 16);
  w.y = o[2] | ((unsigned)o[3] << 16);
  w.z = o[4] | ((unsigned)o[5] << 16);
  w.w = o[6] | ((unsigned)o[7] << 16);
  *(uint4*)(dst + idx) = w;
}

// ---------------------------------------------------------------------------
// Hidden-layer GEMM: m97-structure 128x128 tile (unchanged, passing).
// ---------------------------------------------------------------------------
__global__ __launch_bounds__(256) void gemm_bt_k(
    const unsigned short* __restrict__ A,
    const unsigned short* __restrict__ Bw,
    const float* __restrict__ scale,
    const float* __restrict__ bias,
    unsigned short* __restrict__ Cout,
    int M, int N, int K)
{
  __shared__ unsigned short As[128 * 64];
  __shared__ unsigned short Bs[128 * 64];

  const int tid  = threadIdx.x;
  const int lane = tid & 63;
  const int wid  = tid >> 6;
  const int wm   = wid >> 1;
  const int wn   = wid & 1;

  const int mBase = blockIdx.y * 128;
  const int nBase = blockIdx.x * 128;

  const int srow = lane >> 3;
  const int skel = (lane & 7) * 8;

  f32x4 acc[4][4];
  #pragma unroll
  for (int i = 0; i < 4; ++i)
    #pragma unroll
    for (int j = 0; j < 4; ++j)
      acc[i][j] = (f32x4){0.f, 0.f, 0.f, 0.f};

  for (int k0 = 0; k0 < K; k0 += 64) {
    #pragma unroll
    for (int j = 0; j < 4; ++j) {
      const int c = wid * 4 + j;
      const int row = c * 8 + srow;
      load_lds16(A  + (size_t)(mBase + row) * K + (k0 + skel), As + c * 512);
      load_lds16(Bw + (size_t)(nBase + row) * K + (k0 + skel), Bs + c * 512);
    }
    __syncthreads();

    #pragma unroll
    for (int s = 0; s < 2; ++s) {
      const int kk = s * 32 + (lane >> 4) * 8;
      bf16x8 af[4], bfr[4];
      #pragma unroll
      for (int i = 0; i < 4; ++i)
        af[i] = *(const bf16x8*)(As + (wm * 64 + i * 16 + (lane & 15)) * 64 + kk);
      #pragma unroll
      for (int j = 0; j < 4; ++j)
        bfr[j] = *(const bf16x8*)(Bs + (wn * 64 + j * 16 + (lane & 15)) * 64 + kk);
      #pragma unroll
      for (int i = 0; i < 4; ++i)
        #pragma unroll
        for (int j = 0; j < 4; ++j)
          acc[i][j] = __builtin_amdgcn_mfma_f32_16x16x32_bf16(af[i], bfr[j], acc[i][j], 0, 0, 0);
    }
    __syncthreads();
  }

  const int lr = lane >> 4;
  const int lc = lane & 15;
  #pragma unroll
  for (int j = 0; j < 4; ++j) {
    const int col = nBase + wn * 64 + j * 16 + lc;
    const float sc = scale[col];
    const float bs = bias[col];
    #pragma unroll
    for (int i = 0; i < 4; ++i) {
      const int r0 = mBase + wm * 64 + i * 16 + lr * 4;
      #pragma unroll
      for (int r = 0; r < 4; ++r) {
        float vv = fmaxf(acc[i][j][r] * sc + bs, 0.0f);
        Cout[(size_t)(r0 + r) * N + col] = f2bf(vv);
      }
    }
  }
}

// ---------------------------------------------------------------------------
// Final GEMM, 8-phase schedule with ASM ds_reads (counted waits authoritative):
// 256x256 tile, BK=64, 8 waves (2M x 4N), double-buffered LDS, 4 phases/tile.
// Phase p issues asm ds_read_b128 for phase p+1's A frags (read-ahead) and
// waits lgkmcnt(4) so phase-p operands are ready while next reads fly under
// the MFMA cluster.  vmcnt(4) once per K-tile (2 half-tiles stay in flight).
// Stage slotting: A(t+1) at phases 0,1 ; B(t+2) at phases 2,3.
// LDS XOR swizzle via pre-swizzled global source + swizzled read addr.
// ---------------------------------------------------------------------------
__global__ __launch_bounds__(512) void gemm256_final_k(
    const unsigned short* __restrict__ A,
    const unsigned short* __restrict__ Bw,
    const float* __restrict__ scale,
    const float* __restrict__ bias,
    float* __restrict__ C,
    int M, int N, int K)
{
  __shared__ unsigned short As[2 * 16384];
  __shared__ unsigned short Bs[2 * 16384];

  const int tid  = threadIdx.x;
  const int lane = tid & 63;
  const int wid  = tid >> 6;   // 0..7
  const int wm   = wid >> 2;   // 0..1  (128-row half)
  const int wn   = wid & 3;    // 0..3  (64-col quarter)
  const int l15  = lane & 15;
  const int l4   = lane >> 4;

  // bijective XCD swizzle (2000 = 8*250), then m-fastest for B reuse
  const int q    = gridDim.x >> 3;
  const int wgid = (blockIdx.x & 7) * q + (blockIdx.x >> 3);
  const int mBase = (wgid & 15) << 8;
  const int nBase = (wgid >> 4) << 8;

  const int gsw = ((lane & 7) ^ (lane >> 3)) * 8;   // pre-swizzled src granule

  auto stage_half = [&](const unsigned short* __restrict__ G, int growBase,
                        int kcol, unsigned short* ldsHalf) {
    #pragma unroll
    for (int j = 0; j < 2; ++j)
      load_lds16(G + (size_t)(growBase + j * 64 + wid * 8 + (lane >> 3)) * K + kcol + gsw,
                 ldsHalf + j * 4096 + wid * 512);
  };

  // LDS byte bases for asm ds_reads
  const unsigned asLds = (unsigned)(size_t)(const LDS_AS unsigned short*)As;
  const unsigned bsLds = (unsigned)(size_t)(const LDS_AS unsigned short*)Bs;

  // A frag byte offset within a 128-row half: rh*128 + ((gg ^ (rh&7))*16)
  auto read_a = [&](bf16x8 (&dst)[2][2], int ip, unsigned aTile) {
    #pragma unroll
    for (int ii = 0; ii < 2; ++ii)
      #pragma unroll
      for (int s = 0; s < 2; ++s) {
        const int rh = (ip * 2 + ii) * 16 + l15;
        const int gg = s * 4 + l4;
        unsigned off = aTile + (unsigned)(rh * 128 + ((gg ^ (rh & 7)) * 16));
        asm volatile("ds_read_b128 %0, %1" : "=&v"(dst[ii][s]) : "v"(off));
      }
  };

  f32x4 acc[8][4];
  #pragma unroll
  for (int i = 0; i < 8; ++i)
    #pragma unroll
    for (int j = 0; j < 4; ++j)
      acc[i][j] = (f32x4){0.f, 0.f, 0.f, 0.f};

  const int nt = K >> 6;   // 32 K-tiles

  // prologue: fully stage tiles 0 and 1
  stage_half(A,  mBase,       0,  As);
  stage_half(A,  mBase + 128, 0,  As + 8192);
  stage_half(Bw, nBase,       0,  Bs);
  stage_half(Bw, nBase + 128, 0,  Bs + 8192);
  stage_half(A,  mBase,       64, As + 16384);
  stage_half(A,  mBase + 128, 64, As + 16384 + 8192);
  stage_half(Bw, nBase,       64, Bs + 16384);
  stage_half(Bw, nBase + 128, 64, Bs + 16384 + 8192);
  asm volatile("s_waitcnt vmcnt(8)" ::: "memory");   // tile 0 landed
  __builtin_amdgcn_s_barrier();

  bf16x8 bfr[4][2];     // B frags, live across the tile
  bf16x8 afA[2][2], afB[2][2];

  for (int t = 0; t < nt; ++t) {
    const unsigned aTile = asLds + ((unsigned)(t & 1) << 15) + ((unsigned)wm << 14);
    const unsigned bTile = bsLds + ((unsigned)(t & 1) << 15);

    #pragma unroll
    for (int ip = 0; ip < 4; ++ip) {
      // ---- issue asm ds_reads (read-ahead) ----
      if (ip == 0) {
        #pragma unroll
        for (int j = 0; j < 4; ++j)
          #pragma unroll
          for (int s = 0; s < 2; ++s) {
            const int br = wn * 64 + j * 16 + l15;
            const int gg = s * 4 + l4;
            unsigned off = bTile + (unsigned)((br >> 7) * 16384 + (br & 127) * 128 +
                                              ((gg ^ (br & 7)) * 16));
            asm volatile("ds_read_b128 %0, %1" : "=&v"(bfr[j][s]) : "v"(off));
          }
        read_a(afA, 0, aTile);   // phase-0 frags
        read_a(afB, 1, aTile);   // phase-1 frags (read-ahead)
      } else if (ip == 1) {
        read_a(afA, 2, aTile);   // phase-2 frags
      } else if (ip == 2) {
        read_a(afB, 3, aTile);   // phase-3 frags
      }

      // ---- stage one half-tile ----
      if (ip == 0) { if (t >= 1 && t + 1 < nt)
        stage_half(A,  mBase,       (t + 1) * 64, As + ((t + 1) & 1) * 16384); }
      if (ip == 1) { if (t >= 1 && t + 1 < nt)
        stage_half(A,  mBase + 128, (t + 1) * 64, As + ((t + 1) & 1) * 16384 + 8192); }
      if (ip == 2) { if (t + 2 < nt)
        stage_half(Bw, nBase,       (t + 2) * 64, Bs + (t & 1) * 16384); }
      if (ip == 3) { if (t + 2 < nt)
        stage_half(Bw, nBase + 128, (t + 2) * 64, Bs + (t & 1) * 16384 + 8192); }

      __builtin_amdgcn_sched_barrier(0);
      __builtin_amdgcn_s_barrier();
      // retire this phase's operands; next phase's 4 A-reads stay in flight
      if (ip == 3) asm volatile("s_waitcnt lgkmcnt(0)" ::: "memory");
      else         asm volatile("s_waitcnt lgkmcnt(4)" ::: "memory");
      __builtin_amdgcn_sched_barrier(0);   // rule #18: MFMA must not hoist above

      const bf16x8 (&af)[2][2] = (ip & 1) ? afB : afA;
      __builtin_amdgcn_s_setprio(1);
      #pragma unroll
      for (int ii = 0; ii < 2; ++ii)
        #pragma unroll
        for (int j = 0; j < 4; ++j) {
          acc[ip * 2 + ii][j] = __builtin_amdgcn_mfma_f32_16x16x32_bf16(
              af[ii][0], bfr[j][0], acc[ip * 2 + ii][j], 0, 0, 0);
          acc[ip * 2 + ii][j] = __builtin_amdgcn_mfma_f32_16x16x32_bf16(
              af[ii][1], bfr[j][1], acc[ip * 2 + ii][j], 0, 0, 0);
        }
      __builtin_amdgcn_s_setprio(0);
      __builtin_amdgcn_sched_barrier(0);

      if (ip == 3) {
        if (t + 2 < nt) asm volatile("s_waitcnt vmcnt(4)" ::: "memory");
        else            asm volatile("s_waitcnt vmcnt(0)" ::: "memory");
      }
      __builtin_amdgcn_s_barrier();
    }
  }

  // epilogue: C/D layout col = lane&15, row = (lane>>4)*4 + reg
  const int lr = l4;
  const int lc = l15;
  #pragma unroll
  for (int j = 0; j < 4; ++j) {
    const int col = nBase + wn * 64 + j * 16 + lc;
    const float sc = scale[col];
    const float bs = bias[col];
    #pragma unroll
    for (int i = 0; i < 8; ++i) {
      const int r0 = mBase + wm * 128 + i * 16 + lr * 4;
      #pragma unroll
      for (int r = 0; r < 4; ++r)
        C[(size_t)(r0 + r) * N + col] = acc[i][j][r] * sc + bs;
    }
  }
}

// ---------------------------------------------------------------------------
extern "C" void kernel_launch(void* const* d_in, const int* in_sizes, int n_in,
                              void* d_out, int out_size, void* d_ws, size_t ws_size,
                              hipStream_t stream) {
  const int V = 32000, H = 2048, L = 4, M = 4096;
  const int*   ids         = (const int*)d_in[0];
  const float* emb         = (const float*)d_in[1];
  const void*  layer_wq    = d_in[2];
  const float* layer_scale = (const float*)d_in[3];
  const float* layer_bias  = (const float*)d_in[4];
  const void*  out_wq      = d_in[5];
  const float* out_scale   = (const float*)d_in[6];
  const float* out_bias    = (const float*)d_in[7];
  float* out = (float*)d_out;

  char* ws = (char*)d_ws;
  const size_t xBytes = (size_t)M * H * 2;
  unsigned short* xA = (unsigned short*)(ws);
  unsigned short* xB = (unsigned short*)(ws + xBytes);
  unsigned short* lw = (unsigned short*)(ws + 2 * xBytes);
  unsigned short* ow = (unsigned short*)(ws + 2 * xBytes + (size_t)L * H * H * 2);
  int* flag = (int*)(ws + 2 * xBytes + (size_t)L * H * H * 2 + (size_t)V * H * 2);

  detect_dtype_k<<<1, 256, 0, stream>>>((const int*)layer_wq, flag);
  gather_emb_k<<<M, 256, 0, stream>>>(ids, emb, xA);
  convert_w_k<<<(L * H * H) / 2048, 256, 0, stream>>>(layer_wq, lw, flag);
  convert_w_k<<<(V * H) / 2048, 256, 0, stream>>>(out_wq, ow, flag);

  dim3 blk(256);
  dim3 gh(H / 128, M / 128);
  unsigned short* xin = xA;
  unsigned short* xout = xB;
  for (int i = 0; i < L; ++i) {
    gemm_bt_k<<<gh, blk, 0, stream>>>(xin, lw + (size_t)i * H * H,
                                      layer_scale + i * H, layer_bias + i * H,
                                      xout, M, H, H);
    unsigned short* t = xin; xin = xout; xout = t;
  }
  // final: (M/256)*(V/256) = 16*125 = 2000 blocks
  gemm256_final_k<<<dim3(2000), dim3(512), 0, stream>>>(
      xin, ow, out_scale, out_bias, out, M, V, H);
}

// Round 5
// 911.744 us; speedup vs baseline: 1.2455x; 1.0390x over previous
//
#include <hip/hip_runtime.h>
#include <hip/hip_bf16.h>
#include <stdint.h>
#include <stddef.h>

#define GLOBAL_AS __attribute__((address_space(1)))
#define LDS_AS __attribute__((address_space(3)))

typedef __attribute__((ext_vector_type(4))) float f32x4;
typedef __attribute__((ext_vector_type(8))) short bf16x8;

template<int N> struct ICn { static constexpr int value = N; };

__device__ __forceinline__ unsigned short f2bf(float f) {
  unsigned u = __float_as_uint(f);
  u += 0x7FFFu + ((u >> 16) & 1u);   // round-to-nearest-even
  return (unsigned short)(u >> 16);
}

__device__ __forceinline__ void load_lds16(const void* g, void* l) {
  __builtin_amdgcn_global_load_lds((const GLOBAL_AS void*)g, (LDS_AS void*)l, 16, 0, 0);
}

// ds_read_b128 with compile-time offset immediate; address VALU-free.
template<int IMM>
__device__ __forceinline__ void ds_read128(bf16x8 &d, unsigned addr) {
  asm volatile("ds_read_b128 %0, %1 offset:%c2"
               : "=&v"(d) : "v"(addr), "i"(IMM));
}

// ---------------------------------------------------------------------------
// Detect int8 vs int32 storage of the ternary weights (see round-0 notes).
// ---------------------------------------------------------------------------
__global__ __launch_bounds__(256) void detect_dtype_k(const int* __restrict__ w,
                                                      int* __restrict__ flag) {
  __shared__ int bad;
  if (threadIdx.x == 0) bad = 0;
  __syncthreads();
  int b = 0;
  for (int i = threadIdx.x; i < 4096; i += 256) {
    int v = w[i];
    if (v < -1 || v > 1) b = 1;
  }
  if (b) bad = 1;
  __syncthreads();
  if (threadIdx.x == 0) *flag = bad ? 0 : 1;
}

// ---------------------------------------------------------------------------
// x0[t][h] = bf16(emb[ids[t]][h])
// ---------------------------------------------------------------------------
__global__ __launch_bounds__(256) void gather_emb_k(const int* __restrict__ ids,
                                                    const float* __restrict__ emb,
                                                    unsigned short* __restrict__ x) {
  const int t = blockIdx.x;
  const int row = ids[t];
  const float4* src = (const float4*)(emb + (size_t)row * 2048);
  const int e = threadIdx.x;
  float4 a = src[e * 2], b = src[e * 2 + 1];
  uint4 o;
  o.x = f2bf(a.x) | ((unsigned)f2bf(a.y) << 16);
  o.y = f2bf(a.z) | ((unsigned)f2bf(a.w) << 16);
  o.z = f2bf(b.x) | ((unsigned)f2bf(b.y) << 16);
  o.w = f2bf(b.z) | ((unsigned)f2bf(b.w) << 16);
  *(uint4*)(x + (size_t)t * 2048 + e * 8) = o;
}

// ---------------------------------------------------------------------------
// ternary int8-or-int32 -> bf16
// ---------------------------------------------------------------------------
__global__ __launch_bounds__(256) void convert_w_k(const void* __restrict__ src,
                                                   unsigned short* __restrict__ dst,
                                                   const int* __restrict__ flag) {
  const long long idx = ((long long)blockIdx.x * 256 + threadIdx.x) * 8;
  int v[8];
  if (*flag) {
    const int* s = (const int*)src + idx;
    const int4 a = *(const int4*)s;
    const int4 b = *(const int4*)(s + 4);
    v[0] = a.x; v[1] = a.y; v[2] = a.z; v[3] = a.w;
    v[4] = b.x; v[5] = b.y; v[6] = b.z; v[7] = b.w;
  } else {
    const uint2 u = *(const uint2*)((const char*)src + idx);
    v[0] = (char)(u.x); v[1] = (char)(u.x >> 8); v[2] = (char)(u.x >> 16); v[3] = (char)(u.x >> 24);
    v[4] = (char)(u.y); v[5] = (char)(u.y >> 8); v[6] = (char)(u.y >> 16); v[7] = (char)(u.y >> 24);
  }
  unsigned short o[8];
  #pragma unroll
  for (int k = 0; k < 8; ++k)
    o[k] = (v[k] == 0) ? 0 : ((v[k] > 0) ? 0x3F80 : 0xBF80);
  uint4 w;
  w.x = o[0] | ((unsigned)o[1] << 16);
  w.y = o[2] | ((unsigned)o[3] << 16);
  w.z = o[4] | ((unsigned)o[5] << 16);
  w.w = o[6] | ((unsigned)o[7] << 16);
  *(uint4*)(dst + idx) = w;
}

// ---------------------------------------------------------------------------
// Hidden-layer GEMM: m97-structure 128x128 tile (unchanged, passing).
// ---------------------------------------------------------------------------
__global__ __launch_bounds__(256) void gemm_bt_k(
    const unsigned short* __restrict__ A,
    const unsigned short* __restrict__ Bw,
    const float* __restrict__ scale,
    const float* __restrict__ bias,
    unsigned short* __restrict__ Cout,
    int M, int N, int K)
{
  __shared__ unsigned short As[128 * 64];
  __shared__ unsigned short Bs[128 * 64];

  const int tid  = threadIdx.x;
  const int lane = tid & 63;
  const int wid  = tid >> 6;
  const int wm   = wid >> 1;
  const int wn   = wid & 1;

  const int mBase = blockIdx.y * 128;
  const int nBase = blockIdx.x * 128;

  const int srow = lane >> 3;
  const int skel = (lane & 7) * 8;

  f32x4 acc[4][4];
  #pragma unroll
  for (int i = 0; i < 4; ++i)
    #pragma unroll
    for (int j = 0; j < 4; ++j)
      acc[i][j] = (f32x4){0.f, 0.f, 0.f, 0.f};

  for (int k0 = 0; k0 < K; k0 += 64) {
    #pragma unroll
    for (int j = 0; j < 4; ++j) {
      const int c = wid * 4 + j;
      const int row = c * 8 + srow;
      load_lds16(A  + (size_t)(mBase + row) * K + (k0 + skel), As + c * 512);
      load_lds16(Bw + (size_t)(nBase + row) * K + (k0 + skel), Bs + c * 512);
    }
    __syncthreads();

    #pragma unroll
    for (int s = 0; s < 2; ++s) {
      const int kk = s * 32 + (lane >> 4) * 8;
      bf16x8 af[4], bfr[4];
      #pragma unroll
      for (int i = 0; i < 4; ++i)
        af[i] = *(const bf16x8*)(As + (wm * 64 + i * 16 + (lane & 15)) * 64 + kk);
      #pragma unroll
      for (int j = 0; j < 4; ++j)
        bfr[j] = *(const bf16x8*)(Bs + (wn * 64 + j * 16 + (lane & 15)) * 64 + kk);
      #pragma unroll
      for (int i = 0; i < 4; ++i)
        #pragma unroll
        for (int j = 0; j < 4; ++j)
          acc[i][j] = __builtin_amdgcn_mfma_f32_16x16x32_bf16(af[i], bfr[j], acc[i][j], 0, 0, 0);
    }
    __syncthreads();
  }

  const int lr = lane >> 4;
  const int lc = lane & 15;
  #pragma unroll
  for (int j = 0; j < 4; ++j) {
    const int col = nBase + wn * 64 + j * 16 + lc;
    const float sc = scale[col];
    const float bs = bias[col];
    #pragma unroll
    for (int i = 0; i < 4; ++i) {
      const int r0 = mBase + wm * 64 + i * 16 + lr * 4;
      #pragma unroll
      for (int r = 0; r < 4; ++r) {
        float vv = fmaxf(acc[i][j][r] * sc + bs, 0.0f);
        Cout[(size_t)(r0 + r) * N + col] = f2bf(vv);
      }
    }
  }
}

// ---------------------------------------------------------------------------
// Final GEMM, 8-phase schedule, zero per-phase address VALU:
// all ds_read addresses live in 4 persistent VGPRs; phase/row/parity offsets
// are compile-time ds_read immediates (K-loop unrolled x2 so buffer parity is
// constexpr). Stage pointers persistent, advanced by +64 elems per use.
// 256x256 tile, BK=64, 8 waves (2Mx4N), dbuf LDS, vmcnt(4)/lgkm(4) counted
// waits, setprio MFMA clusters, XOR swizzle via pre-swizzled global source.
// ---------------------------------------------------------------------------

#define RD_B4() do { \
  ds_read128<PAR*32768 +    0>(bfr[0][0], vB0); ds_read128<PAR*32768 +    0>(bfr[0][1], vB1); \
  ds_read128<PAR*32768 + 2048>(bfr[1][0], vB0); ds_read128<PAR*32768 + 2048>(bfr[1][1], vB1); \
  ds_read128<PAR*32768 + 4096>(bfr[2][0], vB0); ds_read128<PAR*32768 + 4096>(bfr[2][1], vB1); \
  ds_read128<PAR*32768 + 6144>(bfr[3][0], vB0); ds_read128<PAR*32768 + 6144>(bfr[3][1], vB1); \
} while (0)

#define RD_A2(dst, R) do { \
  ds_read128<PAR*32768 + (R)*2048       >(dst[0][0], vA0); ds_read128<PAR*32768 + (R)*2048       >(dst[0][1], vA1); \
  ds_read128<PAR*32768 + (R)*2048 + 2048>(dst[1][0], vA0); ds_read128<PAR*32768 + (R)*2048 + 2048>(dst[1][1], vA1); \
} while (0)

#define STAGE_A(h) do { if (t >= 1 && t + 1 < nt) { \
  load_lds16(pA[h][0], As + (PAR ^ 1) * 16384 + (h) * 8192 +        wid * 512); \
  load_lds16(pA[h][1], As + (PAR ^ 1) * 16384 + (h) * 8192 + 4096 + wid * 512); \
  pA[h][0] += 64; pA[h][1] += 64; } } while (0)

#define STAGE_B(h) do { if (t + 2 < nt) { \
  load_lds16(pB[h][0], Bs + PAR * 16384 + (h) * 8192 +        wid * 512); \
  load_lds16(pB[h][1], Bs + PAR * 16384 + (h) * 8192 + 4096 + wid * 512); \
  pB[h][0] += 64; pB[h][1] += 64; } } while (0)

#define PH_SYNC(LG) \
  __builtin_amdgcn_sched_barrier(0); \
  __builtin_amdgcn_s_barrier(); \
  asm volatile("s_waitcnt lgkmcnt(" #LG ")" ::: "memory"); \
  __builtin_amdgcn_sched_barrier(0);

#define MFMA_PH(IP, AF) \
  __builtin_amdgcn_s_setprio(1); \
  { _Pragma("unroll") for (int ii = 0; ii < 2; ++ii) { \
      _Pragma("unroll") for (int j = 0; j < 4; ++j) { \
        acc[(IP)*2+ii][j] = __builtin_amdgcn_mfma_f32_16x16x32_bf16(AF[ii][0], bfr[j][0], acc[(IP)*2+ii][j], 0, 0, 0); \
        acc[(IP)*2+ii][j] = __builtin_amdgcn_mfma_f32_16x16x32_bf16(AF[ii][1], bfr[j][1], acc[(IP)*2+ii][j], 0, 0, 0); \
  } } } \
  __builtin_amdgcn_s_setprio(0); \
  __builtin_amdgcn_sched_barrier(0);

__global__ __launch_bounds__(512) void gemm256_final_k(
    const unsigned short* __restrict__ A,
    const unsigned short* __restrict__ Bw,
    const float* __restrict__ scale,
    const float* __restrict__ bias,
    float* __restrict__ C,
    int M, int N, int K)
{
  __shared__ unsigned short As[2 * 16384];
  __shared__ unsigned short Bs[2 * 16384];

  const int tid  = threadIdx.x;
  const int lane = tid & 63;
  const int wid  = tid >> 6;   // 0..7
  const int wm   = wid >> 2;   // 0..1  (128-row half)
  const int wn   = wid & 3;    // 0..3  (64-col quarter)
  const int l15  = lane & 15;
  const int l4   = lane >> 4;

  // bijective XCD swizzle (2000 = 8*250), then m-fastest for B reuse
  const int q    = gridDim.x >> 3;
  const int wgid = (blockIdx.x & 7) * q + (blockIdx.x >> 3);
  const int mBase = (wgid & 15) << 8;
  const int nBase = (wgid >> 4) << 8;

  const int gsw = ((lane & 7) ^ (lane >> 3)) * 8;   // pre-swizzled src granule

  // persistent ds_read base addresses (buffer-0, phase-0 relative)
  const unsigned asB = (unsigned)(size_t)(const LDS_AS unsigned short*)As;
  const unsigned bsB = (unsigned)(size_t)(const LDS_AS unsigned short*)Bs;
  const unsigned x7  = (unsigned)(l15 & 7);
  const unsigned vA0 = asB + (wm << 14) + l15 * 128 + ((((unsigned)l4    ) ^ x7) << 4);
  const unsigned vA1 = asB + (wm << 14) + l15 * 128 + ((((unsigned)l4 + 4) ^ x7) << 4);
  const unsigned vB0 = bsB + (wn << 13) + l15 * 128 + ((((unsigned)l4    ) ^ x7) << 4);
  const unsigned vB1 = bsB + (wn << 13) + l15 * 128 + ((((unsigned)l4 + 4) ^ x7) << 4);

  // persistent stage source pointers [half][j]
  const unsigned short* pA[2][2];
  const unsigned short* pB[2][2];
  #pragma unroll
  for (int h = 0; h < 2; ++h)
    #pragma unroll
    for (int j = 0; j < 2; ++j) {
      const int row = h * 128 + j * 64 + wid * 8 + (lane >> 3);
      pA[h][j] = A  + (size_t)(mBase + row) * K + gsw;
      pB[h][j] = Bw + (size_t)(nBase + row) * K + gsw;
    }

  f32x4 acc[8][4];
  #pragma unroll
  for (int i = 0; i < 8; ++i)
    #pragma unroll
    for (int j = 0; j < 4; ++j)
      acc[i][j] = (f32x4){0.f, 0.f, 0.f, 0.f};

  const int nt = K >> 6;   // 32 K-tiles (even)

  // prologue: stage tile 0 (8 instrs) then tile 1 (8 instrs)
  #pragma unroll
  for (int h = 0; h < 2; ++h)
    #pragma unroll
    for (int j = 0; j < 2; ++j)
      load_lds16(pA[h][j], As + h * 8192 + j * 4096 + wid * 512);
  #pragma unroll
  for (int h = 0; h < 2; ++h)
    #pragma unroll
    for (int j = 0; j < 2; ++j)
      load_lds16(pB[h][j], Bs + h * 8192 + j * 4096 + wid * 512);
  #pragma unroll
  for (int h = 0; h < 2; ++h)
    #pragma unroll
    for (int j = 0; j < 2; ++j)
      load_lds16(pA[h][j] + 64, As + 16384 + h * 8192 + j * 4096 + wid * 512);
  #pragma unroll
  for (int h = 0; h < 2; ++h)
    #pragma unroll
    for (int j = 0; j < 2; ++j)
      load_lds16(pB[h][j] + 64, Bs + 16384 + h * 8192 + j * 4096 + wid * 512);
  #pragma unroll
  for (int h = 0; h < 2; ++h)
    #pragma unroll
    for (int j = 0; j < 2; ++j) { pA[h][j] += 128; pB[h][j] += 128; }

  asm volatile("s_waitcnt vmcnt(8)" ::: "memory");   // tile 0 landed
  __builtin_amdgcn_s_barrier();

  bf16x8 bfr[4][2];                 // B frags, live across the tile
  bf16x8 afA[2][2], afB[2][2];      // A frag ping-pong

  auto tile_body = [&](int t, auto par_c) {
    constexpr int PAR = decltype(par_c)::value;
    // ---- ip0 ----
    RD_B4();
    RD_A2(afA, 0);            // phase-0 rows
    RD_A2(afB, 2);            // phase-1 rows (read-ahead)
    STAGE_A(0);
    PH_SYNC(4)                // retire B + afA; afB in flight
    MFMA_PH(0, afA)
    __builtin_amdgcn_s_barrier();
    // ---- ip1 ----
    RD_A2(afA, 4);            // phase-2 rows
    STAGE_A(1);
    PH_SYNC(4)                // retire afB(p1)
    MFMA_PH(1, afB)
    __builtin_amdgcn_s_barrier();
    // ---- ip2 ----
    RD_A2(afB, 6);            // phase-3 rows
    STAGE_B(0);
    PH_SYNC(4)                // retire afA(p2)
    MFMA_PH(2, afA)
    __builtin_amdgcn_s_barrier();
    // ---- ip3 ----
    STAGE_B(1);
    PH_SYNC(0)                // retire afB(p3)
    MFMA_PH(3, afB)
    if (t + 2 < nt) asm volatile("s_waitcnt vmcnt(4)" ::: "memory");
    else            asm volatile("s_waitcnt vmcnt(0)" ::: "memory");
    __builtin_amdgcn_s_barrier();
  };

  for (int t = 0; t < nt; t += 2) {
    tile_body(t,     ICn<0>{});
    tile_body(t + 1, ICn<1>{});
  }

  // epilogue: C/D layout col = lane&15, row = (lane>>4)*4 + reg
  const int lr = l4;
  const int lc = l15;
  #pragma unroll
  for (int j = 0; j < 4; ++j) {
    const int col = nBase + wn * 64 + j * 16 + lc;
    const float sc = scale[col];
    const float bs = bias[col];
    #pragma unroll
    for (int i = 0; i < 8; ++i) {
      const int r0 = mBase + wm * 128 + i * 16 + lr * 4;
      #pragma unroll
      for (int r = 0; r < 4; ++r)
        C[(size_t)(r0 + r) * N + col] = acc[i][j][r] * sc + bs;
    }
  }
}

// ---------------------------------------------------------------------------
extern "C" void kernel_launch(void* const* d_in, const int* in_sizes, int n_in,
                              void* d_out, int out_size, void* d_ws, size_t ws_size,
                              hipStream_t stream) {
  const int V = 32000, H = 2048, L = 4, M = 4096;
  const int*   ids         = (const int*)d_in[0];
  const float* emb         = (const float*)d_in[1];
  const void*  layer_wq    = d_in[2];
  const float* layer_scale = (const float*)d_in[3];
  const float* layer_bias  = (const float*)d_in[4];
  const void*  out_wq      = d_in[5];
  const float* out_scale   = (const float*)d_in[6];
  const float* out_bias    = (const float*)d_in[7];
  float* out = (float*)d_out;

  char* ws = (char*)d_ws;
  const size_t xBytes = (size_t)M * H * 2;
  unsigned short* xA = (unsigned short*)(ws);
  unsigned short* xB = (unsigned short*)(ws + xBytes);
  unsigned short* lw = (unsigned short*)(ws + 2 * xBytes);
  unsigned short* ow = (unsigned short*)(ws + 2 * xBytes + (size_t)L * H * H * 2);
  int* flag = (int*)(ws + 2 * xBytes + (size_t)L * H * H * 2 + (size_t)V * H * 2);

  detect_dtype_k<<<1, 256, 0, stream>>>((const int*)layer_wq, flag);
  gather_emb_k<<<M, 256, 0, stream>>>(ids, emb, xA);
  convert_w_k<<<(L * H * H) / 2048, 256, 0, stream>>>(layer_wq, lw, flag);
  convert_w_k<<<(V * H) / 2048, 256, 0, stream>>>(out_wq, ow, flag);

  dim3 blk(256);
  dim3 gh(H / 128, M / 128);
  unsigned short* xin = xA;
  unsigned short* xout = xB;
  for (int i = 0; i < L; ++i) {
    gemm_bt_k<<<gh, blk, 0, stream>>>(xin, lw + (size_t)i * H * H,
                                      layer_scale + i * H, layer_bias + i * H,
                                      xout, M, H, H);
    unsigned short* t = xin; xin = xout; xout = t;
  }
  // final: (M/256)*(V/256) = 16*125 = 2000 blocks
  gemm256_final_k<<<dim3(2000), dim3(512), 0, stream>>>(
      xin, ow, out_scale, out_bias, out, M, V, H);
}

// Round 6
// 732.363 us; speedup vs baseline: 1.5506x; 1.2449x over previous
//
#include <hip/hip_runtime.h>
#include <hip/hip_bf16.h>
#include <stdint.h>
#include <stddef.h>

#define GLOBAL_AS __attribute__((address_space(1)))
#define LDS_AS __attribute__((address_space(3)))

typedef __attribute__((ext_vector_type(4))) float f32x4;
typedef __attribute__((ext_vector_type(8))) short bf16x8;
typedef __attribute__((ext_vector_type(4))) int   i32x4;

template<int N> struct ICn { static constexpr int value = N; };

__device__ __forceinline__ unsigned short f2bf(float f) {
  unsigned u = __float_as_uint(f);
  u += 0x7FFFu + ((u >> 16) & 1u);   // round-to-nearest-even
  return (unsigned short)(u >> 16);
}

__device__ __forceinline__ void load_lds16(const void* g, void* l) {
  __builtin_amdgcn_global_load_lds((const GLOBAL_AS void*)g, (LDS_AS void*)l, 16, 0, 0);
}

// ds_read_b128 with compile-time offset immediate; address VALU-free.
template<int IMM, typename T>
__device__ __forceinline__ void ds_read128t(T &d, unsigned addr) {
  asm volatile("ds_read_b128 %0, %1 offset:%c2"
               : "=&v"(d) : "v"(addr), "i"(IMM));
}

// ---------------------------------------------------------------------------
// Detect int8 vs int32 storage of the ternary weights (see round-0 notes).
// ---------------------------------------------------------------------------
__global__ __launch_bounds__(256) void detect_dtype_k(const int* __restrict__ w,
                                                      int* __restrict__ flag) {
  __shared__ int bad;
  if (threadIdx.x == 0) bad = 0;
  __syncthreads();
  int b = 0;
  for (int i = threadIdx.x; i < 4096; i += 256) {
    int v = w[i];
    if (v < -1 || v > 1) b = 1;
  }
  if (b) bad = 1;
  __syncthreads();
  if (threadIdx.x == 0) *flag = bad ? 0 : 1;
}

// ---------------------------------------------------------------------------
// x0[t][h] = bf16(emb[ids[t]][h])
// ---------------------------------------------------------------------------
__global__ __launch_bounds__(256) void gather_emb_k(const int* __restrict__ ids,
                                                    const float* __restrict__ emb,
                                                    unsigned short* __restrict__ x) {
  const int t = blockIdx.x;
  const int row = ids[t];
  const float4* src = (const float4*)(emb + (size_t)row * 2048);
  const int e = threadIdx.x;
  float4 a = src[e * 2], b = src[e * 2 + 1];
  uint4 o;
  o.x = f2bf(a.x) | ((unsigned)f2bf(a.y) << 16);
  o.y = f2bf(a.z) | ((unsigned)f2bf(a.w) << 16);
  o.z = f2bf(b.x) | ((unsigned)f2bf(b.y) << 16);
  o.w = f2bf(b.z) | ((unsigned)f2bf(b.w) << 16);
  *(uint4*)(x + (size_t)t * 2048 + e * 8) = o;
}

// ---------------------------------------------------------------------------
// ternary int8-or-int32 -> bf16 (hidden-layer weights)
// ---------------------------------------------------------------------------
__global__ __launch_bounds__(256) void convert_w_k(const void* __restrict__ src,
                                                   unsigned short* __restrict__ dst,
                                                   const int* __restrict__ flag) {
  const long long idx = ((long long)blockIdx.x * 256 + threadIdx.x) * 8;
  int v[8];
  if (*flag) {
    const int* s = (const int*)src + idx;
    const int4 a = *(const int4*)s;
    const int4 b = *(const int4*)(s + 4);
    v[0] = a.x; v[1] = a.y; v[2] = a.z; v[3] = a.w;
    v[4] = b.x; v[5] = b.y; v[6] = b.z; v[7] = b.w;
  } else {
    const uint2 u = *(const uint2*)((const char*)src + idx);
    v[0] = (char)(u.x); v[1] = (char)(u.x >> 8); v[2] = (char)(u.x >> 16); v[3] = (char)(u.x >> 24);
    v[4] = (char)(u.y); v[5] = (char)(u.y >> 8); v[6] = (char)(u.y >> 16); v[7] = (char)(u.y >> 24);
  }
  unsigned short o[8];
  #pragma unroll
  for (int k = 0; k < 8; ++k)
    o[k] = (v[k] == 0) ? 0 : ((v[k] > 0) ? 0x3F80 : 0xBF80);
  uint4 w;
  w.x = o[0] | ((unsigned)o[1] << 16);
  w.y = o[2] | ((unsigned)o[3] << 16);
  w.z = o[4] | ((unsigned)o[5] << 16);
  w.w = o[6] | ((unsigned)o[7] << 16);
  *(uint4*)(dst + idx) = w;
}

// ---------------------------------------------------------------------------
// ternary int8-or-int32 -> int8 (output-layer weights)
// ---------------------------------------------------------------------------
__global__ __launch_bounds__(256) void pack_w8_k(const void* __restrict__ src,
                                                 signed char* __restrict__ dst,
                                                 const int* __restrict__ flag) {
  const long long idx = ((long long)blockIdx.x * 256 + threadIdx.x) * 8;
  if (*flag) {   // int32 -> pack to int8
    const int* s = (const int*)src + idx;
    const int4 a = *(const int4*)s;
    const int4 b = *(const int4*)(s + 4);
    uint2 o;
    o.x = ((unsigned)(unsigned char)(signed char)a.x)       |
          ((unsigned)(unsigned char)(signed char)a.y << 8)  |
          ((unsigned)(unsigned char)(signed char)a.z << 16) |
          ((unsigned)(unsigned char)(signed char)a.w << 24);
    o.y = ((unsigned)(unsigned char)(signed char)b.x)       |
          ((unsigned)(unsigned char)(signed char)b.y << 8)  |
          ((unsigned)(unsigned char)(signed char)b.z << 16) |
          ((unsigned)(unsigned char)(signed char)b.w << 24);
    *(uint2*)(dst + idx) = o;
  } else {       // already int8 -> copy
    *(uint2*)(dst + idx) = *(const uint2*)((const char*)src + idx);
  }
}

// ---------------------------------------------------------------------------
// colsum_c = sum_k w8[c][k]  (ternary row sums, fp32 out).  1 wave per col.
// ---------------------------------------------------------------------------
__global__ __launch_bounds__(256) void colsum_k(const signed char* __restrict__ w,
                                                float* __restrict__ cs) {
  const int lane = threadIdx.x & 63;
  const int c = blockIdx.x * 4 + (threadIdx.x >> 6);
  const int4* p = (const int4*)(w + (size_t)c * 2048 + lane * 32);
  const int4 a = p[0], b = p[1];
  int wds[8] = {a.x, a.y, a.z, a.w, b.x, b.y, b.z, b.w};
  int s = 0;
  #pragma unroll
  for (int k = 0; k < 8; ++k)
    #pragma unroll
    for (int bb = 0; bb < 4; ++bb)
      s += (signed char)(wds[k] >> (8 * bb));
  #pragma unroll
  for (int o = 32; o; o >>= 1) s += __shfl_xor(s, o);
  if (lane == 0) cs[c] = (float)s;
}

// ---------------------------------------------------------------------------
// Per-row offset quantization of final x: s=rowmax/255, m=127.5s,
// q = round(x/s - 127.5) in [-128,127].  One block per row.
// ---------------------------------------------------------------------------
__global__ __launch_bounds__(256) void rowquant_k(const unsigned short* __restrict__ x,
                                                  signed char* __restrict__ xq,
                                                  float* __restrict__ srow) {
  __shared__ float wmax[4];
  const int r = blockIdx.x;
  const int e = threadIdx.x;
  const uint4 u = *(const uint4*)(x + (size_t)r * 2048 + e * 8);
  unsigned wds[4] = {u.x, u.y, u.z, u.w};
  float v[8];
  #pragma unroll
  for (int k = 0; k < 4; ++k) {
    v[2 * k]     = __uint_as_float(wds[k] << 16);
    v[2 * k + 1] = __uint_as_float(wds[k] & 0xFFFF0000u);
  }
  float m = 0.0f;                       // x >= 0 post-ReLU
  #pragma unroll
  for (int k = 0; k < 8; ++k) m = fmaxf(m, v[k]);
  #pragma unroll
  for (int o = 32; o; o >>= 1) m = fmaxf(m, __shfl_xor(m, o));
  if ((threadIdx.x & 63) == 0) wmax[threadIdx.x >> 6] = m;
  __syncthreads();
  const float mx = fmaxf(fmaxf(wmax[0], wmax[1]), fmaxf(wmax[2], wmax[3]));
  const float inv = mx > 0.0f ? 255.0f / mx : 0.0f;
  unsigned b[8];
  #pragma unroll
  for (int k = 0; k < 8; ++k) {
    int q = __float2int_rn(v[k] * inv - 127.5f);
    q = q < -128 ? -128 : (q > 127 ? 127 : q);
    b[k] = (unsigned)(unsigned char)(signed char)q;
  }
  uint2 o;
  o.x = b[0] | (b[1] << 8) | (b[2] << 16) | (b[3] << 24);
  o.y = b[4] | (b[5] << 8) | (b[6] << 16) | (b[7] << 24);
  *(uint2*)(xq + (size_t)r * 2048 + e * 8) = o;
  if (threadIdx.x == 0) srow[r] = mx * (1.0f / 255.0f);
}

// ---------------------------------------------------------------------------
// Hidden-layer GEMM: m97-structure 128x128 tile (unchanged, passing).
// ---------------------------------------------------------------------------
__global__ __launch_bounds__(256) void gemm_bt_k(
    const unsigned short* __restrict__ A,
    const unsigned short* __restrict__ Bw,
    const float* __restrict__ scale,
    const float* __restrict__ bias,
    unsigned short* __restrict__ Cout,
    int M, int N, int K)
{
  __shared__ unsigned short As[128 * 64];
  __shared__ unsigned short Bs[128 * 64];

  const int tid  = threadIdx.x;
  const int lane = tid & 63;
  const int wid  = tid >> 6;
  const int wm   = wid >> 1;
  const int wn   = wid & 1;

  const int mBase = blockIdx.y * 128;
  const int nBase = blockIdx.x * 128;

  const int srow = lane >> 3;
  const int skel = (lane & 7) * 8;

  f32x4 acc[4][4];
  #pragma unroll
  for (int i = 0; i < 4; ++i)
    #pragma unroll
    for (int j = 0; j < 4; ++j)
      acc[i][j] = (f32x4){0.f, 0.f, 0.f, 0.f};

  for (int k0 = 0; k0 < K; k0 += 64) {
    #pragma unroll
    for (int j = 0; j < 4; ++j) {
      const int c = wid * 4 + j;
      const int row = c * 8 + srow;
      load_lds16(A  + (size_t)(mBase + row) * K + (k0 + skel), As + c * 512);
      load_lds16(Bw + (size_t)(nBase + row) * K + (k0 + skel), Bs + c * 512);
    }
    __syncthreads();

    #pragma unroll
    for (int s = 0; s < 2; ++s) {
      const int kk = s * 32 + (lane >> 4) * 8;
      bf16x8 af[4], bfr[4];
      #pragma unroll
      for (int i = 0; i < 4; ++i)
        af[i] = *(const bf16x8*)(As + (wm * 64 + i * 16 + (lane & 15)) * 64 + kk);
      #pragma unroll
      for (int j = 0; j < 4; ++j)
        bfr[j] = *(const bf16x8*)(Bs + (wn * 64 + j * 16 + (lane & 15)) * 64 + kk);
      #pragma unroll
      for (int i = 0; i < 4; ++i)
        #pragma unroll
        for (int j = 0; j < 4; ++j)
          acc[i][j] = __builtin_amdgcn_mfma_f32_16x16x32_bf16(af[i], bfr[j], acc[i][j], 0, 0, 0);
    }
    __syncthreads();
  }

  const int lr = lane >> 4;
  const int lc = lane & 15;
  #pragma unroll
  for (int j = 0; j < 4; ++j) {
    const int col = nBase + wn * 64 + j * 16 + lc;
    const float sc = scale[col];
    const float bs = bias[col];
    #pragma unroll
    for (int i = 0; i < 4; ++i) {
      const int r0 = mBase + wm * 64 + i * 16 + lr * 4;
      #pragma unroll
      for (int r = 0; r < 4; ++r) {
        float vv = fmaxf(acc[i][j][r] * sc + bs, 0.0f);
        Cout[(size_t)(r0 + r) * N + col] = f2bf(vv);
      }
    }
  }
}

// ---------------------------------------------------------------------------
// Final GEMM, INT8 8-phase schedule (byte-layout identical to the round-5
// bf16 kernel: rows are 128 B in both).  256x256 tile, BK=128 (int8), 16
// K-tiles, 8 waves (2Mx4N), dbuf LDS (128 KiB), persistent VGPR addresses +
// compile-time ds_read immediates, counted vmcnt(4)/lgkm(4), setprio MFMA,
// XOR swizzle via pre-swizzled global source.
// Epilogue: logit = dotq*(s_r*scale_c) + 127.5*s_r*colsum_c*scale_c + bias_c
// ---------------------------------------------------------------------------

#define RD_B4() do { \
  ds_read128t<PAR*32768 +    0>(bfr[0][0], vB0); ds_read128t<PAR*32768 +    0>(bfr[0][1], vB1); \
  ds_read128t<PAR*32768 + 2048>(bfr[1][0], vB0); ds_read128t<PAR*32768 + 2048>(bfr[1][1], vB1); \
  ds_read128t<PAR*32768 + 4096>(bfr[2][0], vB0); ds_read128t<PAR*32768 + 4096>(bfr[2][1], vB1); \
  ds_read128t<PAR*32768 + 6144>(bfr[3][0], vB0); ds_read128t<PAR*32768 + 6144>(bfr[3][1], vB1); \
} while (0)

#define RD_A2(dst, R) do { \
  ds_read128t<PAR*32768 + (R)*2048       >(dst[0][0], vA0); ds_read128t<PAR*32768 + (R)*2048       >(dst[0][1], vA1); \
  ds_read128t<PAR*32768 + (R)*2048 + 2048>(dst[1][0], vA0); ds_read128t<PAR*32768 + (R)*2048 + 2048>(dst[1][1], vA1); \
} while (0)

#define STAGE_A(h) do { if (t >= 1 && t + 1 < nt) { \
  load_lds16(pA[h][0], As + (PAR ^ 1) * 32768 + (h) * 16384 +        wid * 1024); \
  load_lds16(pA[h][1], As + (PAR ^ 1) * 32768 + (h) * 16384 + 8192 + wid * 1024); \
  pA[h][0] += 128; pA[h][1] += 128; } } while (0)

#define STAGE_B(h) do { if (t + 2 < nt) { \
  load_lds16(pB[h][0], Bs + PAR * 32768 + (h) * 16384 +        wid * 1024); \
  load_lds16(pB[h][1], Bs + PAR * 32768 + (h) * 16384 + 8192 + wid * 1024); \
  pB[h][0] += 128; pB[h][1] += 128; } } while (0)

#define PH_SYNC(LG) \
  __builtin_amdgcn_sched_barrier(0); \
  __builtin_amdgcn_s_barrier(); \
  asm volatile("s_waitcnt lgkmcnt(" #LG ")" ::: "memory"); \
  __builtin_amdgcn_sched_barrier(0);

#define MFMA_PH(IP, AF) \
  __builtin_amdgcn_s_setprio(1); \
  { _Pragma("unroll") for (int ii = 0; ii < 2; ++ii) { \
      _Pragma("unroll") for (int j = 0; j < 4; ++j) { \
        acc[(IP)*2+ii][j] = __builtin_amdgcn_mfma_i32_16x16x64_i8(AF[ii][0], bfr[j][0], acc[(IP)*2+ii][j], 0, 0, 0); \
        acc[(IP)*2+ii][j] = __builtin_amdgcn_mfma_i32_16x16x64_i8(AF[ii][1], bfr[j][1], acc[(IP)*2+ii][j], 0, 0, 0); \
  } } } \
  __builtin_amdgcn_s_setprio(0); \
  __builtin_amdgcn_sched_barrier(0);

__global__ __launch_bounds__(512) void gemm256i8_k(
    const signed char* __restrict__ Aq,
    const signed char* __restrict__ Bq,
    const float* __restrict__ scale,
    const float* __restrict__ bias,
    const float* __restrict__ srow,
    const float* __restrict__ colsum,
    float* __restrict__ C,
    int M, int N, int K)   // K in elements (=bytes)
{
  __shared__ signed char As[2 * 32768];
  __shared__ signed char Bs[2 * 32768];

  const int tid  = threadIdx.x;
  const int lane = tid & 63;
  const int wid  = tid >> 6;   // 0..7
  const int wm   = wid >> 2;   // 0..1  (128-row half)
  const int wn   = wid & 3;    // 0..3  (64-col quarter)
  const int l15  = lane & 15;
  const int l4   = lane >> 4;

  // bijective XCD swizzle (2000 = 8*250), then m-fastest for B reuse
  const int q    = gridDim.x >> 3;
  const int wgid = (blockIdx.x & 7) * q + (blockIdx.x >> 3);
  const int mBase = (wgid & 15) << 8;
  const int nBase = (wgid >> 4) << 8;

  const int gsw = ((lane & 7) ^ (lane >> 3)) * 16;   // pre-swizzled src granule (bytes)

  // persistent ds_read base addresses (buffer-0 relative); rows are 128 B
  const unsigned asB = (unsigned)(size_t)(const LDS_AS signed char*)As;
  const unsigned bsB = (unsigned)(size_t)(const LDS_AS signed char*)Bs;
  const unsigned x7  = (unsigned)(l15 & 7);
  const unsigned vA0 = asB + (wm << 14) + l15 * 128 + ((((unsigned)l4    ) ^ x7) << 4);
  const unsigned vA1 = asB + (wm << 14) + l15 * 128 + ((((unsigned)l4 + 4) ^ x7) << 4);
  const unsigned vB0 = bsB + (wn << 13) + l15 * 128 + ((((unsigned)l4    ) ^ x7) << 4);
  const unsigned vB1 = bsB + (wn << 13) + l15 * 128 + ((((unsigned)l4 + 4) ^ x7) << 4);

  // persistent stage source pointers [half][j]
  const signed char* pA[2][2];
  const signed char* pB[2][2];
  #pragma unroll
  for (int h = 0; h < 2; ++h)
    #pragma unroll
    for (int j = 0; j < 2; ++j) {
      const int row = h * 128 + j * 64 + wid * 8 + (lane >> 3);
      pA[h][j] = Aq + (size_t)(mBase + row) * K + gsw;
      pB[h][j] = Bq + (size_t)(nBase + row) * K + gsw;
    }

  i32x4 acc[8][4];
  #pragma unroll
  for (int i = 0; i < 8; ++i)
    #pragma unroll
    for (int j = 0; j < 4; ++j)
      acc[i][j] = (i32x4){0, 0, 0, 0};

  const int nt = K >> 7;   // 16 K-tiles (even)

  // prologue: stage tile 0 then tile 1 (8 instr each per wave-set)
  #pragma unroll
  for (int h = 0; h < 2; ++h)
    #pragma unroll
    for (int j = 0; j < 2; ++j)
      load_lds16(pA[h][j], As + h * 16384 + j * 8192 + wid * 1024);
  #pragma unroll
  for (int h = 0; h < 2; ++h)
    #pragma unroll
    for (int j = 0; j < 2; ++j)
      load_lds16(pB[h][j], Bs + h * 16384 + j * 8192 + wid * 1024);
  #pragma unroll
  for (int h = 0; h < 2; ++h)
    #pragma unroll
    for (int j = 0; j < 2; ++j)
      load_lds16(pA[h][j] + 128, As + 32768 + h * 16384 + j * 8192 + wid * 1024);
  #pragma unroll
  for (int h = 0; h < 2; ++h)
    #pragma unroll
    for (int j = 0; j < 2; ++j)
      load_lds16(pB[h][j] + 128, Bs + 32768 + h * 16384 + j * 8192 + wid * 1024);
  #pragma unroll
  for (int h = 0; h < 2; ++h)
    #pragma unroll
    for (int j = 0; j < 2; ++j) { pA[h][j] += 256; pB[h][j] += 256; }

  asm volatile("s_waitcnt vmcnt(8)" ::: "memory");   // tile 0 landed
  __builtin_amdgcn_s_barrier();

  i32x4 bfr[4][2];
  i32x4 afA[2][2], afB[2][2];

  auto tile_body = [&](int t, auto par_c) {
    constexpr int PAR = decltype(par_c)::value;
    // ---- ip0 ----
    RD_B4();
    RD_A2(afA, 0);
    RD_A2(afB, 2);            // phase-1 rows (read-ahead)
    STAGE_A(0);
    PH_SYNC(4)
    MFMA_PH(0, afA)
    __builtin_amdgcn_s_barrier();
    // ---- ip1 ----
    RD_A2(afA, 4);
    STAGE_A(1);
    PH_SYNC(4)
    MFMA_PH(1, afB)
    __builtin_amdgcn_s_barrier();
    // ---- ip2 ----
    RD_A2(afB, 6);
    STAGE_B(0);
    PH_SYNC(4)
    MFMA_PH(2, afA)
    __builtin_amdgcn_s_barrier();
    // ---- ip3 ----
    STAGE_B(1);
    PH_SYNC(0)
    MFMA_PH(3, afB)
    if (t + 2 < nt) asm volatile("s_waitcnt vmcnt(4)" ::: "memory");
    else            asm volatile("s_waitcnt vmcnt(0)" ::: "memory");
    __builtin_amdgcn_s_barrier();
  };

  for (int t = 0; t < nt; t += 2) {
    tile_body(t,     ICn<0>{});
    tile_body(t + 1, ICn<1>{});
  }

  // epilogue: C/D layout col = lane&15, row = (lane>>4)*4 + reg (dtype-indep)
  #pragma unroll
  for (int j = 0; j < 4; ++j) {
    const int col = nBase + wn * 64 + j * 16 + l15;
    const float sc  = scale[col];
    const float csc = colsum[col] * sc;
    const float bs  = bias[col];
    #pragma unroll
    for (int i = 0; i < 8; ++i) {
      const int r0 = mBase + wm * 128 + i * 16 + l4 * 4;
      const f32x4 sv = *(const f32x4*)(srow + r0);
      #pragma unroll
      for (int r = 0; r < 4; ++r) {
        const float fa = (float)acc[i][j][r];
        C[(size_t)(r0 + r) * N + col] =
            fmaf(fa, sv[r] * sc, fmaf(127.5f * sv[r], csc, bs));
      }
    }
  }
}

// ---------------------------------------------------------------------------
extern "C" void kernel_launch(void* const* d_in, const int* in_sizes, int n_in,
                              void* d_out, int out_size, void* d_ws, size_t ws_size,
                              hipStream_t stream) {
  const int V = 32000, H = 2048, L = 4, M = 4096;
  const int*   ids         = (const int*)d_in[0];
  const float* emb         = (const float*)d_in[1];
  const void*  layer_wq    = d_in[2];
  const float* layer_scale = (const float*)d_in[3];
  const float* layer_bias  = (const float*)d_in[4];
  const void*  out_wq      = d_in[5];
  const float* out_scale   = (const float*)d_in[6];
  const float* out_bias    = (const float*)d_in[7];
  float* out = (float*)d_out;

  // ws layout (bytes):
  //   xA 0..16M, xB 16M..32M, lw 32M..64M (bf16),
  //   ow8 64M..64M+65.5MB (int8), xq +8.4MB, srow +16KB, colsum +128KB, flag
  char* ws = (char*)d_ws;
  const size_t xBytes = (size_t)M * H * 2;
  unsigned short* xA  = (unsigned short*)(ws);
  unsigned short* xB  = (unsigned short*)(ws + xBytes);
  unsigned short* lw  = (unsigned short*)(ws + 2 * xBytes);
  size_t off = 2 * xBytes + (size_t)L * H * H * 2;
  signed char* ow8    = (signed char*)(ws + off);   off += (size_t)V * H;
  signed char* xq     = (signed char*)(ws + off);   off += (size_t)M * H;
  float* srow         = (float*)(ws + off);         off += (size_t)M * 4;
  float* cs           = (float*)(ws + off);         off += (size_t)V * 4;
  int* flag           = (int*)(ws + off);

  detect_dtype_k<<<1, 256, 0, stream>>>((const int*)layer_wq, flag);
  gather_emb_k<<<M, 256, 0, stream>>>(ids, emb, xA);
  convert_w_k<<<(L * H * H) / 2048, 256, 0, stream>>>(layer_wq, lw, flag);
  pack_w8_k<<<(V * H) / 2048, 256, 0, stream>>>(out_wq, ow8, flag);
  colsum_k<<<V / 4, 256, 0, stream>>>(ow8, cs);

  dim3 blk(256);
  dim3 gh(H / 128, M / 128);
  unsigned short* xin = xA;
  unsigned short* xout = xB;
  for (int i = 0; i < L; ++i) {
    gemm_bt_k<<<gh, blk, 0, stream>>>(xin, lw + (size_t)i * H * H,
                                      layer_scale + i * H, layer_bias + i * H,
                                      xout, M, H, H);
    unsigned short* t = xin; xin = xout; xout = t;
  }

  rowquant_k<<<M, 256, 0, stream>>>(xin, xq, srow);

  // final: (M/256)*(V/256) = 16*125 = 2000 blocks
  gemm256i8_k<<<dim3(2000), dim3(512), 0, stream>>>(
      xq, ow8, out_scale, out_bias, srow, cs, out, M, V, H);
}

// Round 7
// 715.632 us; speedup vs baseline: 1.5868x; 1.0234x over previous
//
#include <hip/hip_runtime.h>
#include <hip/hip_bf16.h>
#include <stdint.h>
#include <stddef.h>

#define GLOBAL_AS __attribute__((address_space(1)))
#define LDS_AS __attribute__((address_space(3)))

typedef __attribute__((ext_vector_type(4))) float f32x4;
typedef __attribute__((ext_vector_type(8))) short bf16x8;
typedef __attribute__((ext_vector_type(4))) int   i32x4;

template<int N> struct ICn { static constexpr int value = N; };

__device__ __forceinline__ unsigned short f2bf(float f) {
  unsigned u = __float_as_uint(f);
  u += 0x7FFFu + ((u >> 16) & 1u);   // round-to-nearest-even
  return (unsigned short)(u >> 16);
}

__device__ __forceinline__ void load_lds16(const void* g, void* l) {
  __builtin_amdgcn_global_load_lds((const GLOBAL_AS void*)g, (LDS_AS void*)l, 16, 0, 0);
}

// ds_read_b128 with compile-time offset immediate; address VALU-free.
template<int IMM, typename T>
__device__ __forceinline__ void ds_read128t(T &d, unsigned addr) {
  asm volatile("ds_read_b128 %0, %1 offset:%c2"
               : "=&v"(d) : "v"(addr), "i"(IMM));
}

// ---------------------------------------------------------------------------
// Detect int8 vs int32 storage of the ternary weights (see round-0 notes).
// ---------------------------------------------------------------------------
__global__ __launch_bounds__(256) void detect_dtype_k(const int* __restrict__ w,
                                                      int* __restrict__ flag) {
  __shared__ int bad;
  if (threadIdx.x == 0) bad = 0;
  __syncthreads();
  int b = 0;
  for (int i = threadIdx.x; i < 4096; i += 256) {
    int v = w[i];
    if (v < -1 || v > 1) b = 1;
  }
  if (b) bad = 1;
  __syncthreads();
  if (threadIdx.x == 0) *flag = bad ? 0 : 1;
}

// ---------------------------------------------------------------------------
// x0[t][h] = bf16(emb[ids[t]][h])
// ---------------------------------------------------------------------------
__global__ __launch_bounds__(256) void gather_emb_k(const int* __restrict__ ids,
                                                    const float* __restrict__ emb,
                                                    unsigned short* __restrict__ x) {
  const int t = blockIdx.x;
  const int row = ids[t];
  const float4* src = (const float4*)(emb + (size_t)row * 2048);
  const int e = threadIdx.x;
  float4 a = src[e * 2], b = src[e * 2 + 1];
  uint4 o;
  o.x = f2bf(a.x) | ((unsigned)f2bf(a.y) << 16);
  o.y = f2bf(a.z) | ((unsigned)f2bf(a.w) << 16);
  o.z = f2bf(b.x) | ((unsigned)f2bf(b.y) << 16);
  o.w = f2bf(b.z) | ((unsigned)f2bf(b.w) << 16);
  *(uint4*)(x + (size_t)t * 2048 + e * 8) = o;
}

// ---------------------------------------------------------------------------
// ternary int8-or-int32 -> bf16 (hidden-layer weights)
// ---------------------------------------------------------------------------
__global__ __launch_bounds__(256) void convert_w_k(const void* __restrict__ src,
                                                   unsigned short* __restrict__ dst,
                                                   const int* __restrict__ flag) {
  const long long idx = ((long long)blockIdx.x * 256 + threadIdx.x) * 8;
  int v[8];
  if (*flag) {
    const int* s = (const int*)src + idx;
    const int4 a = *(const int4*)s;
    const int4 b = *(const int4*)(s + 4);
    v[0] = a.x; v[1] = a.y; v[2] = a.z; v[3] = a.w;
    v[4] = b.x; v[5] = b.y; v[6] = b.z; v[7] = b.w;
  } else {
    const uint2 u = *(const uint2*)((const char*)src + idx);
    v[0] = (char)(u.x); v[1] = (char)(u.x >> 8); v[2] = (char)(u.x >> 16); v[3] = (char)(u.x >> 24);
    v[4] = (char)(u.y); v[5] = (char)(u.y >> 8); v[6] = (char)(u.y >> 16); v[7] = (char)(u.y >> 24);
  }
  unsigned short o[8];
  #pragma unroll
  for (int k = 0; k < 8; ++k)
    o[k] = (v[k] == 0) ? 0 : ((v[k] > 0) ? 0x3F80 : 0xBF80);
  uint4 w;
  w.x = o[0] | ((unsigned)o[1] << 16);
  w.y = o[2] | ((unsigned)o[3] << 16);
  w.z = o[4] | ((unsigned)o[5] << 16);
  w.w = o[6] | ((unsigned)o[7] << 16);
  *(uint4*)(dst + idx) = w;
}

// ---------------------------------------------------------------------------
// ternary int8-or-int32 -> int8 (output-layer weights)
// ---------------------------------------------------------------------------
__global__ __launch_bounds__(256) void pack_w8_k(const void* __restrict__ src,
                                                 signed char* __restrict__ dst,
                                                 const int* __restrict__ flag) {
  const long long idx = ((long long)blockIdx.x * 256 + threadIdx.x) * 8;
  if (*flag) {   // int32 -> pack to int8
    const int* s = (const int*)src + idx;
    const int4 a = *(const int4*)s;
    const int4 b = *(const int4*)(s + 4);
    uint2 o;
    o.x = ((unsigned)(unsigned char)(signed char)a.x)       |
          ((unsigned)(unsigned char)(signed char)a.y << 8)  |
          ((unsigned)(unsigned char)(signed char)a.z << 16) |
          ((unsigned)(unsigned char)(signed char)a.w << 24);
    o.y = ((unsigned)(unsigned char)(signed char)b.x)       |
          ((unsigned)(unsigned char)(signed char)b.y << 8)  |
          ((unsigned)(unsigned char)(signed char)b.z << 16) |
          ((unsigned)(unsigned char)(signed char)b.w << 24);
    *(uint2*)(dst + idx) = o;
  } else {       // already int8 -> copy
    *(uint2*)(dst + idx) = *(const uint2*)((const char*)src + idx);
  }
}

// ---------------------------------------------------------------------------
// colsum_c = sum_k w8[c][k]  (ternary row sums, fp32 out).  1 wave per col.
// ---------------------------------------------------------------------------
__global__ __launch_bounds__(256) void colsum_k(const signed char* __restrict__ w,
                                                float* __restrict__ cs) {
  const int lane = threadIdx.x & 63;
  const int c = blockIdx.x * 4 + (threadIdx.x >> 6);
  const int4* p = (const int4*)(w + (size_t)c * 2048 + lane * 32);
  const int4 a = p[0], b = p[1];
  int wds[8] = {a.x, a.y, a.z, a.w, b.x, b.y, b.z, b.w};
  int s = 0;
  #pragma unroll
  for (int k = 0; k < 8; ++k)
    #pragma unroll
    for (int bb = 0; bb < 4; ++bb)
      s += (signed char)(wds[k] >> (8 * bb));
  #pragma unroll
  for (int o = 32; o; o >>= 1) s += __shfl_xor(s, o);
  if (lane == 0) cs[c] = (float)s;
}

// ---------------------------------------------------------------------------
// Per-row offset quantization of final x: s=rowmax/255, m=127.5s,
// q = round(x/s - 127.5) in [-128,127].  One block per row.
// ---------------------------------------------------------------------------
__global__ __launch_bounds__(256) void rowquant_k(const unsigned short* __restrict__ x,
                                                  signed char* __restrict__ xq,
                                                  float* __restrict__ srow) {
  __shared__ float wmax[4];
  const int r = blockIdx.x;
  const int e = threadIdx.x;
  const uint4 u = *(const uint4*)(x + (size_t)r * 2048 + e * 8);
  unsigned wds[4] = {u.x, u.y, u.z, u.w};
  float v[8];
  #pragma unroll
  for (int k = 0; k < 4; ++k) {
    v[2 * k]     = __uint_as_float(wds[k] << 16);
    v[2 * k + 1] = __uint_as_float(wds[k] & 0xFFFF0000u);
  }
  float m = 0.0f;                       // x >= 0 post-ReLU
  #pragma unroll
  for (int k = 0; k < 8; ++k) m = fmaxf(m, v[k]);
  #pragma unroll
  for (int o = 32; o; o >>= 1) m = fmaxf(m, __shfl_xor(m, o));
  if ((threadIdx.x & 63) == 0) wmax[threadIdx.x >> 6] = m;
  __syncthreads();
  const float mx = fmaxf(fmaxf(wmax[0], wmax[1]), fmaxf(wmax[2], wmax[3]));
  const float inv = mx > 0.0f ? 255.0f / mx : 0.0f;
  unsigned b[8];
  #pragma unroll
  for (int k = 0; k < 8; ++k) {
    int q = __float2int_rn(v[k] * inv - 127.5f);
    q = q < -128 ? -128 : (q > 127 ? 127 : q);
    b[k] = (unsigned)(unsigned char)(signed char)q;
  }
  uint2 o;
  o.x = b[0] | (b[1] << 8) | (b[2] << 16) | (b[3] << 24);
  o.y = b[4] | (b[5] << 8) | (b[6] << 16) | (b[7] << 24);
  *(uint2*)(xq + (size_t)r * 2048 + e * 8) = o;
  if (threadIdx.x == 0) srow[r] = mx * (1.0f / 255.0f);
}

// ---------------------------------------------------------------------------
// Hidden-layer GEMM: m97-structure 128x128 tile (unchanged, passing).
// ---------------------------------------------------------------------------
__global__ __launch_bounds__(256) void gemm_bt_k(
    const unsigned short* __restrict__ A,
    const unsigned short* __restrict__ Bw,
    const float* __restrict__ scale,
    const float* __restrict__ bias,
    unsigned short* __restrict__ Cout,
    int M, int N, int K)
{
  __shared__ unsigned short As[128 * 64];
  __shared__ unsigned short Bs[128 * 64];

  const int tid  = threadIdx.x;
  const int lane = tid & 63;
  const int wid  = tid >> 6;
  const int wm   = wid >> 1;
  const int wn   = wid & 1;

  const int mBase = blockIdx.y * 128;
  const int nBase = blockIdx.x * 128;

  const int srow = lane >> 3;
  const int skel = (lane & 7) * 8;

  f32x4 acc[4][4];
  #pragma unroll
  for (int i = 0; i < 4; ++i)
    #pragma unroll
    for (int j = 0; j < 4; ++j)
      acc[i][j] = (f32x4){0.f, 0.f, 0.f, 0.f};

  for (int k0 = 0; k0 < K; k0 += 64) {
    #pragma unroll
    for (int j = 0; j < 4; ++j) {
      const int c = wid * 4 + j;
      const int row = c * 8 + srow;
      load_lds16(A  + (size_t)(mBase + row) * K + (k0 + skel), As + c * 512);
      load_lds16(Bw + (size_t)(nBase + row) * K + (k0 + skel), Bs + c * 512);
    }
    __syncthreads();

    #pragma unroll
    for (int s = 0; s < 2; ++s) {
      const int kk = s * 32 + (lane >> 4) * 8;
      bf16x8 af[4], bfr[4];
      #pragma unroll
      for (int i = 0; i < 4; ++i)
        af[i] = *(const bf16x8*)(As + (wm * 64 + i * 16 + (lane & 15)) * 64 + kk);
      #pragma unroll
      for (int j = 0; j < 4; ++j)
        bfr[j] = *(const bf16x8*)(Bs + (wn * 64 + j * 16 + (lane & 15)) * 64 + kk);
      #pragma unroll
      for (int i = 0; i < 4; ++i)
        #pragma unroll
        for (int j = 0; j < 4; ++j)
          acc[i][j] = __builtin_amdgcn_mfma_f32_16x16x32_bf16(af[i], bfr[j], acc[i][j], 0, 0, 0);
    }
    __syncthreads();
  }

  const int lr = lane >> 4;
  const int lc = lane & 15;
  #pragma unroll
  for (int j = 0; j < 4; ++j) {
    const int col = nBase + wn * 64 + j * 16 + lc;
    const float sc = scale[col];
    const float bs = bias[col];
    #pragma unroll
    for (int i = 0; i < 4; ++i) {
      const int r0 = mBase + wm * 64 + i * 16 + lr * 4;
      #pragma unroll
      for (int r = 0; r < 4; ++r) {
        float vv = fmaxf(acc[i][j][r] * sc + bs, 0.0f);
        Cout[(size_t)(r0 + r) * N + col] = f2bf(vv);
      }
    }
  }
}

// ---------------------------------------------------------------------------
// Final GEMM, INT8, free-running 2-barrier-per-tile schedule:
// 256x256 tile, BK=128, 16 K-tiles, 8 waves (2Mx4N), dbuf LDS (128 KiB).
// Per tile: 4 MFMA clusters of 16, ds_reads spread and counted (lgkmcnt),
// only 2 s_barriers: (#1) end of p1 — fences STAGE_B overwrite of the
// current B buffer against all waves' p0 B-frag reads (retired at their p0
// lgkm wait); (#2) tile end after vmcnt(4) — fences cross-tile LDS writes.
// Waves drift up to 2 phases -> one wave's LDS burst overlaps the other's
// MFMA cluster on the same SIMD (the LDS-BW/MFMA co-bound fix); setprio(1)
// on MFMA now has role-diversity to arbitrate (T5 prerequisite).
// Epilogue: logit = dotq*(s_r*scale_c) + 127.5*s_r*colsum_c*scale_c + bias_c
// ---------------------------------------------------------------------------

#define RD_B8() do { \
  ds_read128t<PAR*32768 +    0>(bfr[0][0], vB0); ds_read128t<PAR*32768 +    0>(bfr[0][1], vB1); \
  ds_read128t<PAR*32768 + 2048>(bfr[1][0], vB0); ds_read128t<PAR*32768 + 2048>(bfr[1][1], vB1); \
  ds_read128t<PAR*32768 + 4096>(bfr[2][0], vB0); ds_read128t<PAR*32768 + 4096>(bfr[2][1], vB1); \
  ds_read128t<PAR*32768 + 6144>(bfr[3][0], vB0); ds_read128t<PAR*32768 + 6144>(bfr[3][1], vB1); \
} while (0)

#define RD_A2(dst, R) do { \
  ds_read128t<PAR*32768 + (R)*2048       >(dst[0][0], vA0); ds_read128t<PAR*32768 + (R)*2048       >(dst[0][1], vA1); \
  ds_read128t<PAR*32768 + (R)*2048 + 2048>(dst[1][0], vA0); ds_read128t<PAR*32768 + (R)*2048 + 2048>(dst[1][1], vA1); \
} while (0)

#define STAGE_A(h) do { if (t >= 1 && t + 1 < nt) { \
  load_lds16(pA[h][0], As + (PAR ^ 1) * 32768 + (h) * 16384 +        wid * 1024); \
  load_lds16(pA[h][1], As + (PAR ^ 1) * 32768 + (h) * 16384 + 8192 + wid * 1024); \
  pA[h][0] += 128; pA[h][1] += 128; } } while (0)

#define STAGE_B(h) do { if (t + 2 < nt) { \
  load_lds16(pB[h][0], Bs + PAR * 32768 + (h) * 16384 +        wid * 1024); \
  load_lds16(pB[h][1], Bs + PAR * 32768 + (h) * 16384 + 8192 + wid * 1024); \
  pB[h][0] += 128; pB[h][1] += 128; } } while (0)

#define SBAR0 __builtin_amdgcn_sched_barrier(0)

#define LGKM_WAIT(LG) \
  SBAR0; \
  asm volatile("s_waitcnt lgkmcnt(" #LG ")" ::: "memory"); \
  SBAR0;

#define MFMA_PH(IP, AF) \
  __builtin_amdgcn_s_setprio(1); \
  { _Pragma("unroll") for (int ii = 0; ii < 2; ++ii) { \
      _Pragma("unroll") for (int j = 0; j < 4; ++j) { \
        acc[(IP)*2+ii][j] = __builtin_amdgcn_mfma_i32_16x16x64_i8(AF[ii][0], bfr[j][0], acc[(IP)*2+ii][j], 0, 0, 0); \
        acc[(IP)*2+ii][j] = __builtin_amdgcn_mfma_i32_16x16x64_i8(AF[ii][1], bfr[j][1], acc[(IP)*2+ii][j], 0, 0, 0); \
  } } } \
  __builtin_amdgcn_s_setprio(0); \
  SBAR0;

__global__ __launch_bounds__(512) void gemm256i8_k(
    const signed char* __restrict__ Aq,
    const signed char* __restrict__ Bq,
    const float* __restrict__ scale,
    const float* __restrict__ bias,
    const float* __restrict__ srow,
    const float* __restrict__ colsum,
    float* __restrict__ C,
    int M, int N, int K)   // K in elements (=bytes)
{
  __shared__ signed char As[2 * 32768];
  __shared__ signed char Bs[2 * 32768];

  const int tid  = threadIdx.x;
  const int lane = tid & 63;
  const int wid  = tid >> 6;   // 0..7
  const int wm   = wid >> 2;   // 0..1  (128-row half)
  const int wn   = wid & 3;    // 0..3  (64-col quarter)
  const int l15  = lane & 15;
  const int l4   = lane >> 4;

  // bijective XCD swizzle (2000 = 8*250), then m-fastest for B reuse
  const int q    = gridDim.x >> 3;
  const int wgid = (blockIdx.x & 7) * q + (blockIdx.x >> 3);
  const int mBase = (wgid & 15) << 8;
  const int nBase = (wgid >> 4) << 8;

  const int gsw = ((lane & 7) ^ (lane >> 3)) * 16;   // pre-swizzled src granule (bytes)

  // persistent ds_read base addresses (buffer-0 relative); rows are 128 B
  const unsigned asB = (unsigned)(size_t)(const LDS_AS signed char*)As;
  const unsigned bsB = (unsigned)(size_t)(const LDS_AS signed char*)Bs;
  const unsigned x7  = (unsigned)(l15 & 7);
  const unsigned vA0 = asB + (wm << 14) + l15 * 128 + ((((unsigned)l4    ) ^ x7) << 4);
  const unsigned vA1 = asB + (wm << 14) + l15 * 128 + ((((unsigned)l4 + 4) ^ x7) << 4);
  const unsigned vB0 = bsB + (wn << 13) + l15 * 128 + ((((unsigned)l4    ) ^ x7) << 4);
  const unsigned vB1 = bsB + (wn << 13) + l15 * 128 + ((((unsigned)l4 + 4) ^ x7) << 4);

  // persistent stage source pointers [half][j]
  const signed char* pA[2][2];
  const signed char* pB[2][2];
  #pragma unroll
  for (int h = 0; h < 2; ++h)
    #pragma unroll
    for (int j = 0; j < 2; ++j) {
      const int row = h * 128 + j * 64 + wid * 8 + (lane >> 3);
      pA[h][j] = Aq + (size_t)(mBase + row) * K + gsw;
      pB[h][j] = Bq + (size_t)(nBase + row) * K + gsw;
    }

  i32x4 acc[8][4];
  #pragma unroll
  for (int i = 0; i < 8; ++i)
    #pragma unroll
    for (int j = 0; j < 4; ++j)
      acc[i][j] = (i32x4){0, 0, 0, 0};

  const int nt = K >> 7;   // 16 K-tiles (even)

  // prologue: stage tile 0 then tile 1 (8 instr each per wave)
  #pragma unroll
  for (int h = 0; h < 2; ++h)
    #pragma unroll
    for (int j = 0; j < 2; ++j)
      load_lds16(pA[h][j], As + h * 16384 + j * 8192 + wid * 1024);
  #pragma unroll
  for (int h = 0; h < 2; ++h)
    #pragma unroll
    for (int j = 0; j < 2; ++j)
      load_lds16(pB[h][j], Bs + h * 16384 + j * 8192 + wid * 1024);
  #pragma unroll
  for (int h = 0; h < 2; ++h)
    #pragma unroll
    for (int j = 0; j < 2; ++j)
      load_lds16(pA[h][j] + 128, As + 32768 + h * 16384 + j * 8192 + wid * 1024);
  #pragma unroll
  for (int h = 0; h < 2; ++h)
    #pragma unroll
    for (int j = 0; j < 2; ++j)
      load_lds16(pB[h][j] + 128, Bs + 32768 + h * 16384 + j * 8192 + wid * 1024);
  #pragma unroll
  for (int h = 0; h < 2; ++h)
    #pragma unroll
    for (int j = 0; j < 2; ++j) { pA[h][j] += 256; pB[h][j] += 256; }

  asm volatile("s_waitcnt vmcnt(8)" ::: "memory");   // tile 0 landed
  __builtin_amdgcn_s_barrier();

  i32x4 bfr[4][2];
  i32x4 afP[2][2], afQ[2][2];       // A frag ping-pong (rows 01/45 vs 23/67)

  auto tile_body = [&](int t, auto par_c) {
    constexpr int PAR = decltype(par_c)::value;
    // ---- p0 : issue rows01 + all B + rows23 (16 reads); wait first 12 ----
    RD_A2(afP, 0);
    RD_B8();
    RD_A2(afQ, 2);
    STAGE_A(0);
    LGKM_WAIT(4)               // rows01 + B retired; rows23 in flight
    MFMA_PH(0, afP)
    // ---- p1 ----
    RD_A2(afP, 4);
    STAGE_A(1);
    LGKM_WAIT(4)               // rows23 retired; rows45 in flight
    MFMA_PH(1, afQ)
    __builtin_amdgcn_s_barrier();   // #1: all waves' B-frag reads retired
    // ---- p2 ----
    RD_A2(afQ, 6);
    STAGE_B(0);
    LGKM_WAIT(4)               // rows45 retired; rows67 in flight
    MFMA_PH(2, afP)
    // ---- p3 ----
    STAGE_B(1);
    LGKM_WAIT(0)               // rows67 retired
    MFMA_PH(3, afQ)
    if (t + 2 < nt) asm volatile("s_waitcnt vmcnt(4)" ::: "memory");
    else            asm volatile("s_waitcnt vmcnt(0)" ::: "memory");
    __builtin_amdgcn_s_barrier();   // #2: tile end (A(t+1)/B(t+1) landed)
  };

  for (int t = 0; t < nt; t += 2) {
    tile_body(t,     ICn<0>{});
    tile_body(t + 1, ICn<1>{});
  }

  // epilogue: C/D layout col = lane&15, row = (lane>>4)*4 + reg (dtype-indep)
  #pragma unroll
  for (int j = 0; j < 4; ++j) {
    const int col = nBase + wn * 64 + j * 16 + l15;
    const float sc  = scale[col];
    const float csc = colsum[col] * sc;
    const float bs  = bias[col];
    #pragma unroll
    for (int i = 0; i < 8; ++i) {
      const int r0 = mBase + wm * 128 + i * 16 + l4 * 4;
      const f32x4 sv = *(const f32x4*)(srow + r0);
      #pragma unroll
      for (int r = 0; r < 4; ++r) {
        const float fa = (float)acc[i][j][r];
        C[(size_t)(r0 + r) * N + col] =
            fmaf(fa, sv[r] * sc, fmaf(127.5f * sv[r], csc, bs));
      }
    }
  }
}

// ---------------------------------------------------------------------------
extern "C" void kernel_launch(void* const* d_in, const int* in_sizes, int n_in,
                              void* d_out, int out_size, void* d_ws, size_t ws_size,
                              hipStream_t stream) {
  const int V = 32000, H = 2048, L = 4, M = 4096;
  const int*   ids         = (const int*)d_in[0];
  const float* emb         = (const float*)d_in[1];
  const void*  layer_wq    = d_in[2];
  const float* layer_scale = (const float*)d_in[3];
  const float* layer_bias  = (const float*)d_in[4];
  const void*  out_wq      = d_in[5];
  const float* out_scale   = (const float*)d_in[6];
  const float* out_bias    = (const float*)d_in[7];
  float* out = (float*)d_out;

  // ws layout (bytes):
  //   xA 0..16M, xB 16M..32M, lw 32M..64M (bf16),
  //   ow8 64M..64M+65.5MB (int8), xq +8.4MB, srow +16KB, colsum +128KB, flag
  char* ws = (char*)d_ws;
  const size_t xBytes = (size_t)M * H * 2;
  unsigned short* xA  = (unsigned short*)(ws);
  unsigned short* xB  = (unsigned short*)(ws + xBytes);
  unsigned short* lw  = (unsigned short*)(ws + 2 * xBytes);
  size_t off = 2 * xBytes + (size_t)L * H * H * 2;
  signed char* ow8    = (signed char*)(ws + off);   off += (size_t)V * H;
  signed char* xq     = (signed char*)(ws + off);   off += (size_t)M * H;
  float* srow         = (float*)(ws + off);         off += (size_t)M * 4;
  float* cs           = (float*)(ws + off);         off += (size_t)V * 4;
  int* flag           = (int*)(ws + off);

  detect_dtype_k<<<1, 256, 0, stream>>>((const int*)layer_wq, flag);
  gather_emb_k<<<M, 256, 0, stream>>>(ids, emb, xA);
  convert_w_k<<<(L * H * H) / 2048, 256, 0, stream>>>(layer_wq, lw, flag);
  pack_w8_k<<<(V * H) / 2048, 256, 0, stream>>>(out_wq, ow8, flag);
  colsum_k<<<V / 4, 256, 0, stream>>>(ow8, cs);

  dim3 blk(256);
  dim3 gh(H / 128, M / 128);
  unsigned short* xin = xA;
  unsigned short* xout = xB;
  for (int i = 0; i < L; ++i) {
    gemm_bt_k<<<gh, blk, 0, stream>>>(xin, lw + (size_t)i * H * H,
                                      layer_scale + i * H, layer_bias + i * H,
                                      xout, M, H, H);
    unsigned short* t = xin; xin = xout; xout = t;
  }

  rowquant_k<<<M, 256, 0, stream>>>(xin, xq, srow);

  // final: (M/256)*(V/256) = 16*125 = 2000 blocks
  gemm256i8_k<<<dim3(2000), dim3(512), 0, stream>>>(
      xq, ow8, out_scale, out_bias, srow, cs, out, M, V, H);
}